// Round 1
// baseline (272.800 us; speedup 1.0000x reference)
//
#include <hip/hip_runtime.h>

#define NB 64
#define NT 512
#define NH 1024
#define NC 8
#define NK 3
#define BT (NB*NT)             // 32768
#define LOGITS_N (NK*BT*NC)    // 786432

// DPP controls
#define QP1  0xB1   // quad_perm [1,0,3,2] -> lane^1
#define QP2  0x4E   // quad_perm [2,3,0,1] -> lane^2
#define ROR4 0x124  // row_ror:4  -> lane^4 (may flip bit3: only safe when value replicated across 8-groups)
#define ROR8 0x128  // row_ror:8  -> exact lane^8 within 16-row
#define HM   0x141  // row_half_mirror -> exact lane^7 within 8

template<int CTRL>
__device__ __forceinline__ float dppf(float x) {
  return __int_as_float(__builtin_amdgcn_update_dpp(0, __float_as_int(x), CTRL, 0xF, 0xF, true));
}
template<int CTRL>
__device__ __forceinline__ int dppi(int x) {
  return __builtin_amdgcn_update_dpp(0, x, CTRL, 0xF, 0xF, true);
}

// ---------- init: transpose W -> Wt[h][24], zero loss -----------------------
// (bias is now folded into proj's epilogue; no 3MB logits pre-fill needed)
__global__ __launch_bounds__(256) void init_kernel(const float* __restrict__ W,
                                                   float* __restrict__ Wt,
                                                   float* __restrict__ out) {
  int i = blockIdx.x * 256 + threadIdx.x;
  if (i < 24 * NH) {
    int h = i / 24, j = i - h * 24;
    int kk = j >> 3, cc = j & 7;
    Wt[i] = W[kk * NC * NH + cc * NH + h];   // Wt[h*24 + j]
  }
  if (i == 0) out[0] = 0.0f;
}

// ---------- proj v8: contiguous 1KB-run staging, full-H blocks, no atomics --
// 512 blocks x 256 thr. Block = 64 rows x full H=1024. 4 chunks of 256 cols.
// Stage: per wave-instruction one contiguous 1KB quarter-row (lane*16B runs),
// XOR-swizzled float4 slots in LDS so the lane<->row ds_read_b128 in compute
// is bank-schedulable. Loads for ch+1 issued before compute(ch) so HBM latency
// hides under the FMA phase; per-block chunk rotation spreads channel phase.
__global__ __launch_bounds__(256, 2) void proj_kernel(const float* __restrict__ enc,
                                                      const float* __restrict__ Wt,
                                                      const float* __restrict__ bias,
                                                      float* __restrict__ out) {
  __shared__ float smem[64 * 256];           // 64KB stage tile (reused by epilogue)
  const int tid = threadIdx.x;
  const int lane = tid & 63;
  const int w = tid >> 6;
  const int row0 = blockIdx.x * 64;
  const int chrot = blockIdx.x & 3;
  const float* eb = enc + (size_t)row0 * 1024;

  float acc[24];
#pragma unroll
  for (int j = 0; j < 24; ++j) acc[j] = 0.0f;

  float4 pf[16];
  auto loadStage = [&](int ci) {
    const int cx = ci ^ chrot;
    // wave w loads rows r = i*4 + w; each instr = 64 lanes x 16B = 1KB contiguous
    const float* p = eb + (size_t)w * 1024 + cx * 256 + lane * 4;
#pragma unroll
    for (int i = 0; i < 16; ++i)
      pf[i] = *(const float4*)(p + (size_t)i * 4096);
  };
  auto writeStage = [&]() {
#pragma unroll
    for (int i = 0; i < 16; ++i) {
      const int r = i * 4 + w;
      const int slot = lane ^ (r & 7);       // XOR-swizzle within 128B stripe
      *(float4*)&smem[r * 256 + slot * 4] = pf[i];
    }
  };

  loadStage(0);
  writeStage();

#pragma unroll 1
  for (int ch = 0; ch < 4; ++ch) {
    __syncthreads();                          // stage(ch) visible to all waves
    if (ch < 3) loadStage(ch + 1);            // issue next chunk's loads early
    const int cx = ch ^ chrot;
    const float* wbase = Wt + __builtin_amdgcn_readfirstlane((cx * 256 + w * 64) * 24);
#pragma unroll 4
    for (int hh = 0; hh < 16; ++hh) {
      const int slot = (w * 16 + hh) ^ (lane & 7);
      float4 e4 = *(const float4*)&smem[lane * 256 + slot * 4];  // lane = row
      const float ev[4] = {e4.x, e4.y, e4.z, e4.w};
      const float* wr = wbase + hh * 96;      // 4 h x 24 (scalar-uniform)
#pragma unroll
      for (int m = 0; m < 4; ++m) {
        const float e = ev[m];
        const float* wm = wr + m * 24;
#pragma unroll
        for (int j = 0; j < 24; ++j) acc[j] = fmaf(e, wm[j], acc[j]);
      }
    }
    __syncthreads();                          // all waves done reading smem(ch)
    if (ch < 3) writeStage();                 // ds_writes (loads landed during compute)
  }

  // epilogue: cross-wave reduce (each wave covered a distinct h-quarter) + bias
  float* sp = smem + w * 1792;
#pragma unroll
  for (int j4 = 0; j4 < 24; j4 += 4)
    *(float4*)&sp[lane * 28 + j4] = make_float4(acc[j4], acc[j4+1], acc[j4+2], acc[j4+3]);
  __syncthreads();
  const int r = tid >> 2, j0 = (tid & 3) * 6;
#pragma unroll
  for (int u = 0; u < 6; ++u) {
    const int j = j0 + u;
    float s = smem[0 * 1792 + r * 28 + j] + smem[1 * 1792 + r * 28 + j]
            + smem[2 * 1792 + r * 28 + j] + smem[3 * 1792 + r * 28 + j] + bias[j];
    out[1 + (size_t)(j >> 3) * (BT * 8) + (size_t)(row0 + r) * 8 + (j & 7)] = s;
  }
}

// ---------- CRF v6: chunk-parallel scan (unchanged) --------------------------
// 384 blocks x 512 thr. blocks 0..191: forward+loss (seq=blockIdx);
// 192..383: viterbi+preds. 1 seq per block; 32 chunks of 16 transitions.
// Phase1: 8 waves build 8x8 chunk transfer matrices (lane=(p,c), DPP within 8).
// Phase2: wave0 32-step scan; fwd waves1-7 do numerator concurrently.
// Vit: exact bp recompute from boundary vectors (tie-exact), parallel backtrace.
__global__ __launch_bounds__(512) void crf_kernel(const int* __restrict__ labels,
                                                  const float* __restrict__ startT,
                                                  const float* __restrict__ endT,
                                                  const float* __restrict__ trans,
                                                  float* __restrict__ d_out) {
  __shared__ float sA[32 * 64];          // chunk matrices [i][p][c]
  __shared__ float sVB[32 * 8];          // vit boundary vectors
  __shared__ int   sBP[512];             // vit packed bp words
  __shared__ int   sMap[32 * 8];         // vit exit->entry maps
  __shared__ int   sEnt[32];             // vit chunk entry states
  __shared__ float sRed[32];             // fwd numerator partials
  __shared__ unsigned char sTags[512];
  __shared__ int sTerm;

  const int tid = threadIdx.x;
  const int lane = tid & 63;
  const int w = tid >> 6;
  const int c = lane & 7;
  const int p = (lane >> 3) & 7;
  const int role = (blockIdx.x >= 192);
  const int seq = role ? blockIdx.x - 192 : blockIdx.x;
  const int k = seq >> 6, b = seq & 63;
  const float* em = d_out + 1 + ((size_t)k * BT + (size_t)b * 512) * 8;
  const float* trk = trans + k * 64;
  const int* lab = labels + b * (NK * NT) + k * NT;

  float Txc[8];
#pragma unroll
  for (int kk = 0; kk < 8; ++kk) Txc[kk] = trk[(c ^ kk) * 8 + c];
  const float Tpc = trk[p * 8 + c];
  const float startc = startT[k * 8 + c];
  const float endc = endT[k * 8 + c];

  if (!role) {
    // ========================= FORWARD (logZ + loss) ========================
    float Mxc[8];
#pragma unroll
    for (int kk = 0; kk < 8; ++kk) Mxc[kk] = __expf(Txc[kk]);

    // phase 1: linear-domain chunk matrices, constant 2^-32 renorm at step 8
#pragma unroll 1
    for (int it = 0; it < 4; ++it) {
      const int i = w * 4 + it;
      const int t0 = i * 16;
      const int te = (t0 + 16 < 512) ? (t0 + 16) : 511;
      float EX[16];
      EX[0] = em[(t0 + 1) * 8 + c];             // raw em for init
#pragma unroll
      for (int j = 1; j < 16; ++j) {
        int t = t0 + 1 + j;
        EX[j] = (t <= te) ? __expf(em[t * 8 + c]) : 1.0f;
      }
      float V = __expf(Tpc + EX[0]);
#pragma unroll
      for (int j = 1; j < 16; ++j) {
        int t = t0 + 1 + j;
        if (t <= te) {
          float x1 = dppf<QP1>(V), x2 = dppf<QP2>(V), x3 = dppf<QP2>(x1);
          float x7 = dppf<HM>(V), x6 = dppf<QP1>(x7), x5 = dppf<QP2>(x7), x4 = dppf<QP2>(x6);
          float s01 = fmaf(x1, Mxc[1], V * Mxc[0]);
          float s23 = fmaf(x3, Mxc[3], x2 * Mxc[2]);
          float s45 = fmaf(x5, Mxc[5], x4 * Mxc[4]);
          float s67 = fmaf(x7, Mxc[7], x6 * Mxc[6]);
          V = ((s01 + s23) + (s45 + s67)) * EX[j];
        }
        if (j == 8) V *= 0x1p-32f;              // exact pow2 renorm (uniform)
      }
      sA[i * 64 + lane] = V;
    }
    __syncthreads();

    float logZ = 0.0f;
    if (w == 0) {
      // phase 2: 32-step alpha scan
      float al = __expf(startc + em[c]);
      float lz = 0.0f;
#pragma unroll 1
      for (int i = 0; i < 32; ++i) {
        const float* Ai = &sA[i * 64];
        float A0 = Ai[(c ^ 0) * 8 + c], A1 = Ai[(c ^ 1) * 8 + c];
        float A2 = Ai[(c ^ 2) * 8 + c], A3 = Ai[(c ^ 3) * 8 + c];
        float A4 = Ai[(c ^ 4) * 8 + c], A5 = Ai[(c ^ 5) * 8 + c];
        float A6 = Ai[(c ^ 6) * 8 + c], A7 = Ai[(c ^ 7) * 8 + c];
        float a1 = dppf<QP1>(al), a2 = dppf<QP2>(al), a3 = dppf<QP2>(a1);
        float a4 = dppf<ROR4>(al), a5 = dppf<ROR4>(a1), a6 = dppf<ROR4>(a2), a7 = dppf<ROR4>(a3);
        float s01 = fmaf(a1, A1, al * A0);
        float s23 = fmaf(a3, A3, a2 * A2);
        float s45 = fmaf(a5, A5, a4 * A4);
        float s67 = fmaf(a7, A7, a6 * A6);
        float s = (s01 + s23) + (s45 + s67);
        float ss = s;
        ss += dppf<QP1>(ss); ss += dppf<QP2>(ss); ss += dppf<ROR4>(ss);
        lz += __logf(ss);
        al = s * (1.0f / ss);
      }
      float se = al * __expf(endc);
      se += dppf<QP1>(se); se += dppf<QP2>(se); se += dppf<ROR4>(se);
      logZ = lz + __logf(se) + 1024.0f * 0.69314718055994531f;  // 32 chunks x 32 ln2
    } else {
      // phase 2 (waves 1-7): gold-path numerator
      int idx = (w - 1) * 64 + lane;            // 0..447
      float ns = 0.0f;
      {
        int tg = lab[idx];
        ns += em[(size_t)idx * 8 + tg] + trk[tg * 8 + lab[idx + 1]];
      }
      if (idx < 64) {
        int t = idx + 448;
        int tg = lab[t];
        ns += em[(size_t)t * 8 + tg];
        if (t < 511) ns += trk[tg * 8 + lab[t + 1]];
      }
      ns += dppf<QP1>(ns); ns += dppf<QP2>(ns); ns += dppf<HM>(ns); ns += dppf<ROR8>(ns);
      if ((lane & 15) == 0) sRed[(w - 1) * 4 + (lane >> 4)] = ns;
    }
    __syncthreads();
    if (tid == 0) {
      float num = startT[k * 8 + lab[0]] + endT[k * 8 + lab[511]];
#pragma unroll
      for (int u = 0; u < 28; ++u) num += sRed[u];
      atomicAdd(d_out, logZ - num);
    }
  } else {
    // ========================= VITERBI (preds) ==============================
    // phase 1: max-plus chunk matrices
#pragma unroll 1
    for (int it = 0; it < 4; ++it) {
      const int i = w * 4 + it;
      const int t0 = i * 16;
      const int te = (t0 + 16 < 512) ? (t0 + 16) : 511;
      float emv[16];
#pragma unroll
      for (int j = 0; j < 16; ++j) {
        int t = t0 + 1 + j;
        emv[j] = (t <= te) ? em[t * 8 + c] : 0.0f;
      }
      float V = Tpc + emv[0];
#pragma unroll
      for (int j = 1; j < 16; ++j) {
        int t = t0 + 1 + j;
        if (t <= te) {
          float x1 = dppf<QP1>(V), x2 = dppf<QP2>(V), x3 = dppf<QP2>(x1);
          float x7 = dppf<HM>(V), x6 = dppf<QP1>(x7), x5 = dppf<QP2>(x7), x4 = dppf<QP2>(x6);
          float c0 = V + Txc[0], c1 = x1 + Txc[1], c2 = x2 + Txc[2], c3 = x3 + Txc[3];
          float c4 = x4 + Txc[4], c5 = x5 + Txc[5], c6 = x6 + Txc[6], c7 = x7 + Txc[7];
          float m0 = fmaxf(fmaxf(c0, c1), c2);
          float m1 = fmaxf(fmaxf(c3, c4), c5);
          float m2 = fmaxf(c6, c7);
          V = fmaxf(fmaxf(m0, m1), m2) + emv[j];
        }
      }
      sA[i * 64 + lane] = V;
    }
    __syncthreads();

    // phase 2: v scan (wave 0), store boundary vectors
    if (w == 0) {
      float v = startc + em[c];
#pragma unroll 1
      for (int i = 0; i < 32; ++i) {
        if (lane < 8) sVB[i * 8 + c] = v;
        const float* Ai = &sA[i * 64];
        float A0 = Ai[(c ^ 0) * 8 + c], A1 = Ai[(c ^ 1) * 8 + c];
        float A2 = Ai[(c ^ 2) * 8 + c], A3 = Ai[(c ^ 3) * 8 + c];
        float A4 = Ai[(c ^ 4) * 8 + c], A5 = Ai[(c ^ 5) * 8 + c];
        float A6 = Ai[(c ^ 6) * 8 + c], A7 = Ai[(c ^ 7) * 8 + c];
        float a1 = dppf<QP1>(v), a2 = dppf<QP2>(v), a3 = dppf<QP2>(a1);
        float a4 = dppf<ROR4>(v), a5 = dppf<ROR4>(a1), a6 = dppf<ROR4>(a2), a7 = dppf<ROR4>(a3);
        float c0 = v + A0, c1 = a1 + A1, c2 = a2 + A2, c3 = a3 + A3;
        float c4 = a4 + A4, c5 = a5 + A5, c6 = a6 + A6, c7 = a7 + A7;
        float m0 = fmaxf(fmaxf(c0, c1), c2);
        float m1 = fmaxf(fmaxf(c3, c4), c5);
        float m2 = fmaxf(c6, c7);
        v = fmaxf(fmaxf(m0, m1), m2);
      }
      float lv = v + endc;
      int li = c;
      {
        float ov; int oi; bool take;
        ov = dppf<QP1>(lv); oi = dppi<QP1>(li);
        take = (ov > lv) || (ov == lv && oi < li); lv = take ? ov : lv; li = take ? oi : li;
        ov = dppf<QP2>(lv); oi = dppi<QP2>(li);
        take = (ov > lv) || (ov == lv && oi < li); lv = take ? ov : lv; li = take ? oi : li;
        ov = dppf<ROR4>(lv); oi = dppi<ROR4>(li);
        take = (ov > lv) || (ov == lv && oi < li); lv = take ? ov : lv; li = take ? oi : li;
      }
      if (lane == 0) sTerm = li;
    }
    __syncthreads();

    // phase 3: exact bp recompute, 8 chunk-slots per wave (waves 0-3)
    if (w < 4) {
      const int u = lane >> 3;
      const int i = w * 8 + u;
      const int t0 = i * 16;
      const int te = (t0 + 16 < 512) ? (t0 + 16) : 511;
      float emv[16];
#pragma unroll
      for (int j = 0; j < 16; ++j) {
        int t = t0 + 1 + j;
        emv[j] = (t <= te) ? em[t * 8 + c] : 0.0f;
      }
      float v = sVB[i * 8 + c];
#pragma unroll
      for (int j = 0; j < 16; ++j) {
        int t = t0 + 1 + j;
        if (t <= te) {
          float x1 = dppf<QP1>(v), x2 = dppf<QP2>(v), x3 = dppf<QP2>(x1);
          float x7 = dppf<HM>(v), x6 = dppf<QP1>(x7), x5 = dppf<QP2>(x7), x4 = dppf<QP2>(x6);
          float c0 = v + Txc[0], c1 = x1 + Txc[1], c2 = x2 + Txc[2], c3 = x3 + Txc[3];
          float c4 = x4 + Txc[4], c5 = x5 + Txc[5], c6 = x6 + Txc[6], c7 = x7 + Txc[7];
          float m0 = fmaxf(fmaxf(c0, c1), c2);
          float m1 = fmaxf(fmaxf(c3, c4), c5);
          float m2 = fmaxf(c6, c7);
          float best = fmaxf(fmaxf(m0, m1), m2);
          int a0 = (c0 == best) ? (c ^ 0) : 8;
          int a1i = (c1 == best) ? (c ^ 1) : 8;
          int a2i = (c2 == best) ? (c ^ 2) : 8;
          int a3i = (c3 == best) ? (c ^ 3) : 8;
          int a4i = (c4 == best) ? (c ^ 4) : 8;
          int a5i = (c5 == best) ? (c ^ 5) : 8;
          int a6i = (c6 == best) ? (c ^ 6) : 8;
          int a7i = (c7 == best) ? (c ^ 7) : 8;
          int arg = min(min(min(a0, a1i), min(a2i, a3i)),
                        min(min(a4i, a5i), min(a6i, a7i)));
          v = best + emv[j];
          int wd = arg << (3 * c);
          wd |= dppi<QP1>(wd); wd |= dppi<QP2>(wd); wd |= dppi<HM>(wd);
          if ((lane & 7) == 0) sBP[t] = wd;
        }
      }
    }
    __syncthreads();

    // phase 4a: per-chunk exit->entry maps (all 8 exit states in parallel)
    if (w < 4) {
      const int u = lane >> 3;
      const int i = w * 8 + u;
      const int t0 = i * 16;
      const int te = (t0 + 16 < 512) ? (t0 + 16) : 511;
      int tag = c;
#pragma unroll
      for (int j = 16; j >= 1; --j) {
        int t = t0 + j;
        if (t <= te) tag = (sBP[t] >> (3 * tag)) & 7;
      }
      sMap[i * 8 + c] = tag;
    }
    __syncthreads();
    // phase 4b: compose maps -> chunk entry states
    if (tid == 0) {
      int cur = sTerm;
#pragma unroll 1
      for (int i = 31; i >= 0; --i) { cur = sMap[i * 8 + cur]; sEnt[i] = cur; }
    }
    __syncthreads();
    // phase 4c: emit tags per chunk (32 parallel lanes)
    if (w == 0 && lane < 32) {
      const int i = lane;
      const int t0 = i * 16;
      const int te = (t0 + 16 < 512) ? (t0 + 16) : 511;
      int tag = (i == 31) ? sTerm : sEnt[i + 1];
      if (i == 31) sTags[511] = (unsigned char)tag;
#pragma unroll
      for (int j = 16; j >= 1; --j) {
        int t = t0 + j;
        if (t <= te) { tag = (sBP[t] >> (3 * tag)) & 7; sTags[t - 1] = (unsigned char)tag; }
      }
    }
    __syncthreads();
    // phase 5: coalesced pred store
    float* outp = d_out + 1 + LOGITS_N + (size_t)seq * 512;
    outp[tid] = (float)sTags[tid];
  }
}

extern "C" void kernel_launch(void* const* d_in, const int* in_sizes, int n_in,
                              void* d_out, int out_size, void* d_ws, size_t ws_size,
                              hipStream_t stream) {
  const float* enc    = (const float*)d_in[0];
  const int*   labels = (const int*)  d_in[1];
  const float* W      = (const float*)d_in[2];
  const float* bias   = (const float*)d_in[3];
  const float* startT = (const float*)d_in[4];
  const float* endT   = (const float*)d_in[5];
  const float* trans  = (const float*)d_in[6];
  float* out = (float*)d_out;
  float* Wt  = (float*)d_ws;   // 24*1024 floats = 96 KB scratch

  init_kernel<<<dim3(96), dim3(256), 0, stream>>>(W, Wt, out);
  proj_kernel<<<dim3(512), dim3(256), 0, stream>>>(enc, Wt, bias, out);
  crf_kernel<<<dim3(384), dim3(512), 0, stream>>>(labels, startT, endT, trans, out);
}

// Round 2
// 268.288 us; speedup vs baseline: 1.0168x; 1.0168x over previous
//
#include <hip/hip_runtime.h>

#define NB 64
#define NT 512
#define NH 1024
#define NC 8
#define NK 3
#define BT (NB*NT)             // 32768
#define LOGITS_N (NK*BT*NC)    // 786432

// DPP controls
#define QP1  0xB1   // quad_perm [1,0,3,2] -> lane^1
#define QP2  0x4E   // quad_perm [2,3,0,1] -> lane^2
#define ROR4 0x124  // row_ror:4  -> lane^4 (may flip bit3: only safe when value replicated across 8-groups)
#define ROR8 0x128  // row_ror:8  -> exact lane^8 within 16-row
#define HM   0x141  // row_half_mirror -> exact lane^7 within 8

template<int CTRL>
__device__ __forceinline__ float dppf(float x) {
  return __int_as_float(__builtin_amdgcn_update_dpp(0, __float_as_int(x), CTRL, 0xF, 0xF, true));
}
template<int CTRL>
__device__ __forceinline__ int dppi(int x) {
  return __builtin_amdgcn_update_dpp(0, x, CTRL, 0xF, 0xF, true);
}

__device__ __forceinline__ void gload_lds16(const float* g, float* l) {
  __builtin_amdgcn_global_load_lds(
      (const __attribute__((address_space(1))) void*)g,
      (__attribute__((address_space(3))) void*)l, 16, 0, 0);
}

// ---------- init: transpose W -> Wt[h][24], zero loss -----------------------
__global__ __launch_bounds__(256) void init_kernel(const float* __restrict__ W,
                                                   float* __restrict__ Wt,
                                                   float* __restrict__ out) {
  int i = blockIdx.x * 256 + threadIdx.x;
  if (i < 24 * NH) {
    int h = i / 24, j = i - h * 24;
    int kk = j >> 3, cc = j & 7;
    Wt[i] = W[kk * NC * NH + cc * NH + h];   // Wt[h*24 + j]
  }
  if (i == 0) out[0] = 0.0f;
}

// ---------- proj v9: global_load_lds double-buffered staging ----------------
// 512 blocks x 256 thr. Block = 64 rows x full H. 8 chunks of 128 cols,
// 2x32KB LDS double buffer staged by __builtin_amdgcn_global_load_lds (16B):
// zero VGPR staging cost, async, counted vmcnt(8) so next chunk's loads stay
// in flight under the FMA phase (T4). LDS dest is linear (HW requirement);
// bank-swizzle done by pre-swizzling the per-lane GLOBAL source (m173) and
// XOR-ing the read slot. Full-H blocks -> plain stores, bias in epilogue.
__global__ __launch_bounds__(256, 2) void proj_kernel(const float* __restrict__ enc,
                                                      const float* __restrict__ Wt,
                                                      const float* __restrict__ bias,
                                                      float* __restrict__ out) {
  __shared__ float smem[2 * 64 * 128];       // 64KB double-buffered stage
  const int tid = threadIdx.x;
  const int lane = tid & 63;
  const int w = tid >> 6;
  const int row0 = blockIdx.x * 64;
  const int chrot = blockIdx.x & 7;
  const float* eb = enc + (size_t)row0 * 1024;

  float acc[24];
#pragma unroll
  for (int j = 0; j < 24; ++j) acc[j] = 0.0f;

  // stage chunk ci into LDS buffer buf. Wave w stages rows [w*16, w*16+16).
  // One instr = 64 lanes x 16B = two 512B row-segments, perfectly coalesced.
  // LDS layout: row r at buf*8192 + r*128; slot s holds global float4 s^(r&7).
  auto stage = [&](int ci, int buf) {
    const int cx = ci ^ chrot;
#pragma unroll
    for (int i = 0; i < 8; ++i) {
      const int r = w * 16 + 2 * i + (lane >> 5);
      const int s = (lane & 31) ^ (r & 7);
      const float* g = eb + (size_t)r * 1024 + cx * 128 + s * 4;
      gload_lds16(g, &smem[buf * 8192 + (w * 16 + 2 * i) * 128]);
    }
  };

  // compute chunk ci from buffer buf. lane = row; wave w covers 32 cols.
  auto compute = [&](int ci, int buf) {
    const int cx = ci ^ chrot;
    const float* wbase = Wt + __builtin_amdgcn_readfirstlane((cx * 128 + w * 32) * 24);
    const float* er = &smem[buf * 8192 + lane * 128];
    const int rx = lane & 7;
#pragma unroll
    for (int hq = 0; hq < 8; ++hq) {
      const int slot = (w * 8 + hq) ^ rx;
      const float4 e4 = *(const float4*)&er[slot * 4];
      const float ev[4] = {e4.x, e4.y, e4.z, e4.w};
      const float* wr = wbase + hq * 96;     // 4 h-rows x 24 (scalar-uniform)
#pragma unroll
      for (int m = 0; m < 4; ++m) {
        const float e = ev[m];
        const float* wm = wr + m * 24;
#pragma unroll
        for (int j = 0; j < 24; ++j) acc[j] = fmaf(e, wm[j], acc[j]);
      }
    }
  };

  stage(0, 0);

#pragma unroll 1
  for (int ci = 0; ci < 8; ++ci) {
    const int buf = ci & 1;
    if (ci < 7) {
      stage(ci + 1, buf ^ 1);
      asm volatile("s_waitcnt vmcnt(8)" ::: "memory");   // chunk-ci loads landed
    } else {
      asm volatile("s_waitcnt vmcnt(0)" ::: "memory");
    }
    __builtin_amdgcn_s_barrier();            // every wave waited its own loads
    asm volatile("" ::: "memory");
    compute(ci, buf);
    asm volatile("" ::: "memory");
    __builtin_amdgcn_s_barrier();            // buf free for next-next stage
  }

  // epilogue: cross-wave reduce (each wave covered a distinct h-slice) + bias
  float* sp = smem + w * 1792;
#pragma unroll
  for (int j4 = 0; j4 < 24; j4 += 4)
    *(float4*)&sp[lane * 28 + j4] = make_float4(acc[j4], acc[j4+1], acc[j4+2], acc[j4+3]);
  __syncthreads();
  const int r = tid >> 2, j0 = (tid & 3) * 6;
#pragma unroll
  for (int u = 0; u < 6; ++u) {
    const int j = j0 + u;
    float s = smem[0 * 1792 + r * 28 + j] + smem[1 * 1792 + r * 28 + j]
            + smem[2 * 1792 + r * 28 + j] + smem[3 * 1792 + r * 28 + j] + bias[j];
    out[1 + (size_t)(j >> 3) * (BT * 8) + (size_t)(row0 + r) * 8 + (j & 7)] = s;
  }
}

// ---------- CRF v6: chunk-parallel scan (unchanged) --------------------------
__global__ __launch_bounds__(512) void crf_kernel(const int* __restrict__ labels,
                                                  const float* __restrict__ startT,
                                                  const float* __restrict__ endT,
                                                  const float* __restrict__ trans,
                                                  float* __restrict__ d_out) {
  __shared__ float sA[32 * 64];          // chunk matrices [i][p][c]
  __shared__ float sVB[32 * 8];          // vit boundary vectors
  __shared__ int   sBP[512];             // vit packed bp words
  __shared__ int   sMap[32 * 8];         // vit exit->entry maps
  __shared__ int   sEnt[32];             // vit chunk entry states
  __shared__ float sRed[32];             // fwd numerator partials
  __shared__ unsigned char sTags[512];
  __shared__ int sTerm;

  const int tid = threadIdx.x;
  const int lane = tid & 63;
  const int w = tid >> 6;
  const int c = lane & 7;
  const int p = (lane >> 3) & 7;
  const int role = (blockIdx.x >= 192);
  const int seq = role ? blockIdx.x - 192 : blockIdx.x;
  const int k = seq >> 6, b = seq & 63;
  const float* em = d_out + 1 + ((size_t)k * BT + (size_t)b * 512) * 8;
  const float* trk = trans + k * 64;
  const int* lab = labels + b * (NK * NT) + k * NT;

  float Txc[8];
#pragma unroll
  for (int kk = 0; kk < 8; ++kk) Txc[kk] = trk[(c ^ kk) * 8 + c];
  const float Tpc = trk[p * 8 + c];
  const float startc = startT[k * 8 + c];
  const float endc = endT[k * 8 + c];

  if (!role) {
    // ========================= FORWARD (logZ + loss) ========================
    float Mxc[8];
#pragma unroll
    for (int kk = 0; kk < 8; ++kk) Mxc[kk] = __expf(Txc[kk]);

    // phase 1: linear-domain chunk matrices, constant 2^-32 renorm at step 8
#pragma unroll 1
    for (int it = 0; it < 4; ++it) {
      const int i = w * 4 + it;
      const int t0 = i * 16;
      const int te = (t0 + 16 < 512) ? (t0 + 16) : 511;
      float EX[16];
      EX[0] = em[(t0 + 1) * 8 + c];             // raw em for init
#pragma unroll
      for (int j = 1; j < 16; ++j) {
        int t = t0 + 1 + j;
        EX[j] = (t <= te) ? __expf(em[t * 8 + c]) : 1.0f;
      }
      float V = __expf(Tpc + EX[0]);
#pragma unroll
      for (int j = 1; j < 16; ++j) {
        int t = t0 + 1 + j;
        if (t <= te) {
          float x1 = dppf<QP1>(V), x2 = dppf<QP2>(V), x3 = dppf<QP2>(x1);
          float x7 = dppf<HM>(V), x6 = dppf<QP1>(x7), x5 = dppf<QP2>(x7), x4 = dppf<QP2>(x6);
          float s01 = fmaf(x1, Mxc[1], V * Mxc[0]);
          float s23 = fmaf(x3, Mxc[3], x2 * Mxc[2]);
          float s45 = fmaf(x5, Mxc[5], x4 * Mxc[4]);
          float s67 = fmaf(x7, Mxc[7], x6 * Mxc[6]);
          V = ((s01 + s23) + (s45 + s67)) * EX[j];
        }
        if (j == 8) V *= 0x1p-32f;              // exact pow2 renorm (uniform)
      }
      sA[i * 64 + lane] = V;
    }
    __syncthreads();

    float logZ = 0.0f;
    if (w == 0) {
      // phase 2: 32-step alpha scan
      float al = __expf(startc + em[c]);
      float lz = 0.0f;
#pragma unroll 1
      for (int i = 0; i < 32; ++i) {
        const float* Ai = &sA[i * 64];
        float A0 = Ai[(c ^ 0) * 8 + c], A1 = Ai[(c ^ 1) * 8 + c];
        float A2 = Ai[(c ^ 2) * 8 + c], A3 = Ai[(c ^ 3) * 8 + c];
        float A4 = Ai[(c ^ 4) * 8 + c], A5 = Ai[(c ^ 5) * 8 + c];
        float A6 = Ai[(c ^ 6) * 8 + c], A7 = Ai[(c ^ 7) * 8 + c];
        float a1 = dppf<QP1>(al), a2 = dppf<QP2>(al), a3 = dppf<QP2>(a1);
        float a4 = dppf<ROR4>(al), a5 = dppf<ROR4>(a1), a6 = dppf<ROR4>(a2), a7 = dppf<ROR4>(a3);
        float s01 = fmaf(a1, A1, al * A0);
        float s23 = fmaf(a3, A3, a2 * A2);
        float s45 = fmaf(a5, A5, a4 * A4);
        float s67 = fmaf(a7, A7, a6 * A6);
        float s = (s01 + s23) + (s45 + s67);
        float ss = s;
        ss += dppf<QP1>(ss); ss += dppf<QP2>(ss); ss += dppf<ROR4>(ss);
        lz += __logf(ss);
        al = s * (1.0f / ss);
      }
      float se = al * __expf(endc);
      se += dppf<QP1>(se); se += dppf<QP2>(se); se += dppf<ROR4>(se);
      logZ = lz + __logf(se) + 1024.0f * 0.69314718055994531f;  // 32 chunks x 32 ln2
    } else {
      // phase 2 (waves 1-7): gold-path numerator
      int idx = (w - 1) * 64 + lane;            // 0..447
      float ns = 0.0f;
      {
        int tg = lab[idx];
        ns += em[(size_t)idx * 8 + tg] + trk[tg * 8 + lab[idx + 1]];
      }
      if (idx < 64) {
        int t = idx + 448;
        int tg = lab[t];
        ns += em[(size_t)t * 8 + tg];
        if (t < 511) ns += trk[tg * 8 + lab[t + 1]];
      }
      ns += dppf<QP1>(ns); ns += dppf<QP2>(ns); ns += dppf<HM>(ns); ns += dppf<ROR8>(ns);
      if ((lane & 15) == 0) sRed[(w - 1) * 4 + (lane >> 4)] = ns;
    }
    __syncthreads();
    if (tid == 0) {
      float num = startT[k * 8 + lab[0]] + endT[k * 8 + lab[511]];
#pragma unroll
      for (int u = 0; u < 28; ++u) num += sRed[u];
      atomicAdd(d_out, logZ - num);
    }
  } else {
    // ========================= VITERBI (preds) ==============================
    // phase 1: max-plus chunk matrices
#pragma unroll 1
    for (int it = 0; it < 4; ++it) {
      const int i = w * 4 + it;
      const int t0 = i * 16;
      const int te = (t0 + 16 < 512) ? (t0 + 16) : 511;
      float emv[16];
#pragma unroll
      for (int j = 0; j < 16; ++j) {
        int t = t0 + 1 + j;
        emv[j] = (t <= te) ? em[t * 8 + c] : 0.0f;
      }
      float V = Tpc + emv[0];
#pragma unroll
      for (int j = 1; j < 16; ++j) {
        int t = t0 + 1 + j;
        if (t <= te) {
          float x1 = dppf<QP1>(V), x2 = dppf<QP2>(V), x3 = dppf<QP2>(x1);
          float x7 = dppf<HM>(V), x6 = dppf<QP1>(x7), x5 = dppf<QP2>(x7), x4 = dppf<QP2>(x6);
          float c0 = V + Txc[0], c1 = x1 + Txc[1], c2 = x2 + Txc[2], c3 = x3 + Txc[3];
          float c4 = x4 + Txc[4], c5 = x5 + Txc[5], c6 = x6 + Txc[6], c7 = x7 + Txc[7];
          float m0 = fmaxf(fmaxf(c0, c1), c2);
          float m1 = fmaxf(fmaxf(c3, c4), c5);
          float m2 = fmaxf(c6, c7);
          V = fmaxf(fmaxf(m0, m1), m2) + emv[j];
        }
      }
      sA[i * 64 + lane] = V;
    }
    __syncthreads();

    // phase 2: v scan (wave 0), store boundary vectors
    if (w == 0) {
      float v = startc + em[c];
#pragma unroll 1
      for (int i = 0; i < 32; ++i) {
        if (lane < 8) sVB[i * 8 + c] = v;
        const float* Ai = &sA[i * 64];
        float A0 = Ai[(c ^ 0) * 8 + c], A1 = Ai[(c ^ 1) * 8 + c];
        float A2 = Ai[(c ^ 2) * 8 + c], A3 = Ai[(c ^ 3) * 8 + c];
        float A4 = Ai[(c ^ 4) * 8 + c], A5 = Ai[(c ^ 5) * 8 + c];
        float A6 = Ai[(c ^ 6) * 8 + c], A7 = Ai[(c ^ 7) * 8 + c];
        float a1 = dppf<QP1>(v), a2 = dppf<QP2>(v), a3 = dppf<QP2>(a1);
        float a4 = dppf<ROR4>(v), a5 = dppf<ROR4>(a1), a6 = dppf<ROR4>(a2), a7 = dppf<ROR4>(a3);
        float c0 = v + A0, c1 = a1 + A1, c2 = a2 + A2, c3 = a3 + A3;
        float c4 = a4 + A4, c5 = a5 + A5, c6 = a6 + A6, c7 = a7 + A7;
        float m0 = fmaxf(fmaxf(c0, c1), c2);
        float m1 = fmaxf(fmaxf(c3, c4), c5);
        float m2 = fmaxf(c6, c7);
        v = fmaxf(fmaxf(m0, m1), m2);
      }
      float lv = v + endc;
      int li = c;
      {
        float ov; int oi; bool take;
        ov = dppf<QP1>(lv); oi = dppi<QP1>(li);
        take = (ov > lv) || (ov == lv && oi < li); lv = take ? ov : lv; li = take ? oi : li;
        ov = dppf<QP2>(lv); oi = dppi<QP2>(li);
        take = (ov > lv) || (ov == lv && oi < li); lv = take ? ov : lv; li = take ? oi : li;
        ov = dppf<ROR4>(lv); oi = dppi<ROR4>(li);
        take = (ov > lv) || (ov == lv && oi < li); lv = take ? ov : lv; li = take ? oi : li;
      }
      if (lane == 0) sTerm = li;
    }
    __syncthreads();

    // phase 3: exact bp recompute, 8 chunk-slots per wave (waves 0-3)
    if (w < 4) {
      const int u = lane >> 3;
      const int i = w * 8 + u;
      const int t0 = i * 16;
      const int te = (t0 + 16 < 512) ? (t0 + 16) : 511;
      float emv[16];
#pragma unroll
      for (int j = 0; j < 16; ++j) {
        int t = t0 + 1 + j;
        emv[j] = (t <= te) ? em[t * 8 + c] : 0.0f;
      }
      float v = sVB[i * 8 + c];
#pragma unroll
      for (int j = 0; j < 16; ++j) {
        int t = t0 + 1 + j;
        if (t <= te) {
          float x1 = dppf<QP1>(v), x2 = dppf<QP2>(v), x3 = dppf<QP2>(x1);
          float x7 = dppf<HM>(v), x6 = dppf<QP1>(x7), x5 = dppf<QP2>(x7), x4 = dppf<QP2>(x6);
          float c0 = v + Txc[0], c1 = x1 + Txc[1], c2 = x2 + Txc[2], c3 = x3 + Txc[3];
          float c4 = x4 + Txc[4], c5 = x5 + Txc[5], c6 = x6 + Txc[6], c7 = x7 + Txc[7];
          float m0 = fmaxf(fmaxf(c0, c1), c2);
          float m1 = fmaxf(fmaxf(c3, c4), c5);
          float m2 = fmaxf(c6, c7);
          float best = fmaxf(fmaxf(m0, m1), m2);
          int a0 = (c0 == best) ? (c ^ 0) : 8;
          int a1i = (c1 == best) ? (c ^ 1) : 8;
          int a2i = (c2 == best) ? (c ^ 2) : 8;
          int a3i = (c3 == best) ? (c ^ 3) : 8;
          int a4i = (c4 == best) ? (c ^ 4) : 8;
          int a5i = (c5 == best) ? (c ^ 5) : 8;
          int a6i = (c6 == best) ? (c ^ 6) : 8;
          int a7i = (c7 == best) ? (c ^ 7) : 8;
          int arg = min(min(min(a0, a1i), min(a2i, a3i)),
                        min(min(a4i, a5i), min(a6i, a7i)));
          v = best + emv[j];
          int wd = arg << (3 * c);
          wd |= dppi<QP1>(wd); wd |= dppi<QP2>(wd); wd |= dppi<HM>(wd);
          if ((lane & 7) == 0) sBP[t] = wd;
        }
      }
    }
    __syncthreads();

    // phase 4a: per-chunk exit->entry maps (all 8 exit states in parallel)
    if (w < 4) {
      const int u = lane >> 3;
      const int i = w * 8 + u;
      const int t0 = i * 16;
      const int te = (t0 + 16 < 512) ? (t0 + 16) : 511;
      int tag = c;
#pragma unroll
      for (int j = 16; j >= 1; --j) {
        int t = t0 + j;
        if (t <= te) tag = (sBP[t] >> (3 * tag)) & 7;
      }
      sMap[i * 8 + c] = tag;
    }
    __syncthreads();
    // phase 4b: compose maps -> chunk entry states
    if (tid == 0) {
      int cur = sTerm;
#pragma unroll 1
      for (int i = 31; i >= 0; --i) { cur = sMap[i * 8 + cur]; sEnt[i] = cur; }
    }
    __syncthreads();
    // phase 4c: emit tags per chunk (32 parallel lanes)
    if (w == 0 && lane < 32) {
      const int i = lane;
      const int t0 = i * 16;
      const int te = (t0 + 16 < 512) ? (t0 + 16) : 511;
      int tag = (i == 31) ? sTerm : sEnt[i + 1];
      if (i == 31) sTags[511] = (unsigned char)tag;
#pragma unroll
      for (int j = 16; j >= 1; --j) {
        int t = t0 + j;
        if (t <= te) { tag = (sBP[t] >> (3 * tag)) & 7; sTags[t - 1] = (unsigned char)tag; }
      }
    }
    __syncthreads();
    // phase 5: coalesced pred store
    float* outp = d_out + 1 + LOGITS_N + (size_t)seq * 512;
    outp[tid] = (float)sTags[tid];
  }
}

extern "C" void kernel_launch(void* const* d_in, const int* in_sizes, int n_in,
                              void* d_out, int out_size, void* d_ws, size_t ws_size,
                              hipStream_t stream) {
  const float* enc    = (const float*)d_in[0];
  const int*   labels = (const int*)  d_in[1];
  const float* W      = (const float*)d_in[2];
  const float* bias   = (const float*)d_in[3];
  const float* startT = (const float*)d_in[4];
  const float* endT   = (const float*)d_in[5];
  const float* trans  = (const float*)d_in[6];
  float* out = (float*)d_out;
  float* Wt  = (float*)d_ws;   // 24*1024 floats = 96 KB scratch

  init_kernel<<<dim3(96), dim3(256), 0, stream>>>(W, Wt, out);
  proj_kernel<<<dim3(512), dim3(256), 0, stream>>>(enc, Wt, bias, out);
  crf_kernel<<<dim3(384), dim3(512), 0, stream>>>(labels, startT, endT, trans, out);
}

// Round 3
// 251.702 us; speedup vs baseline: 1.0838x; 1.0659x over previous
//
#include <hip/hip_runtime.h>

#define NB 64
#define NT 512
#define NH 1024
#define NC 8
#define NK 3
#define BT (NB*NT)             // 32768
#define LOGITS_N (NK*BT*NC)    // 786432

// DPP controls
#define QP1  0xB1   // quad_perm [1,0,3,2] -> lane^1
#define QP2  0x4E   // quad_perm [2,3,0,1] -> lane^2
#define ROR4 0x124  // row_ror:4  -> lane^4 (may flip bit3: only safe when value replicated across 8-groups)
#define ROR8 0x128  // row_ror:8  -> exact lane^8 within 16-row
#define HM   0x141  // row_half_mirror -> exact lane^7 within 8

template<int CTRL>
__device__ __forceinline__ float dppf(float x) {
  return __int_as_float(__builtin_amdgcn_update_dpp(0, __float_as_int(x), CTRL, 0xF, 0xF, true));
}
template<int CTRL>
__device__ __forceinline__ int dppi(int x) {
  return __builtin_amdgcn_update_dpp(0, x, CTRL, 0xF, 0xF, true);
}

__device__ __forceinline__ void gload_lds16(const float* g, float* l) {
  __builtin_amdgcn_global_load_lds(
      (const __attribute__((address_space(1))) void*)g,
      (__attribute__((address_space(3))) void*)l, 16, 0, 0);
}

// ---------- init: transpose W -> Wt[h][24], zero loss -----------------------
__global__ __launch_bounds__(256) void init_kernel(const float* __restrict__ W,
                                                   float* __restrict__ Wt,
                                                   float* __restrict__ out) {
  int i = blockIdx.x * 256 + threadIdx.x;
  if (i < 24 * NH) {
    int h = i / 24, j = i - h * 24;
    int kk = j >> 3, cc = j & 7;
    Wt[i] = W[kk * NC * NH + cc * NH + h];   // Wt[h*24 + j]
  }
  if (i == 0) out[0] = 0.0f;
}

// ---------- proj v10: 2 rows/lane weight reuse, m97-pattern staging ---------
// 256 blocks x 512 thr (8 waves). Block = 128 rows x full H. 16 chunks of 64
// cols staged via global_load_lds into a 2x32KB double buffer (linear dest,
// XOR-swizzled global source, matching XOR on the ds_read slot). ONE
// __syncthreads per chunk (m97 pattern: its vmcnt(0) drain lands after the
// compute phase, so prefetched loads have a full chunk to arrive).
// Waves split H (wave w owns cols w*8..w*8+7 of each chunk); each lane holds
// acc[2][24] for rows {lane, lane+64} -> each 48-float uniform weight batch
// feeds 192 FMAs (4:1 vs the old 1:1), small enough for SGPR double-buffer.
__global__ __launch_bounds__(512, 1) void proj_kernel(const float* __restrict__ enc,
                                                      const float* __restrict__ Wt,
                                                      const float* __restrict__ bias,
                                                      float* __restrict__ out) {
  __shared__ float smem[25600];            // 100 KB: stage dbuf 64 KB | epilogue 100 KB
  const int tid = threadIdx.x;
  const int lane = tid & 63;
  const int w = tid >> 6;                  // 8 waves
  const int row0 = blockIdx.x * 128;
  const float* eb = enc + (size_t)row0 * 1024;

  float acc0[24], acc1[24];
#pragma unroll
  for (int j = 0; j < 24; ++j) { acc0[j] = 0.0f; acc1[j] = 0.0f; }

  // stage chunk ci (64 cols) into buf. 32 gload_lds16 per block (4 per wave),
  // each = 64 lanes x 16B = 1KB = 4 rows' 256B segments. LDS row r linear at
  // buf*8192 + r*64; slot s holds global float4 s^(r&7) (pre-swizzled source).
  auto stage = [&](int ci, int buf) {
#pragma unroll
    for (int i = 0; i < 4; ++i) {
      const int rbase = w * 16 + i * 4;            // wave-uniform 4-row group
      const int r = rbase + (lane >> 4);
      const int s = (lane & 15) ^ (r & 7);
      gload_lds16(eb + (size_t)r * 1024 + ci * 64 + s * 4,
                  &smem[buf * 8192 + rbase * 64]);
    }
  };

  // compute chunk ci from buf. Wave w covers cols w*8..w*8+7; lane handles
  // rows lane and lane+64. Weights: 192 consecutive floats, uniform (SGPR).
  auto compute = [&](int ci, int buf) {
    const float* wp = Wt + __builtin_amdgcn_readfirstlane((ci * 64 + w * 8) * 24);
    const int sw = lane & 7;                       // (lane+64)&7 == lane&7
    const float* r0 = &smem[buf * 8192 + lane * 64];
    const float* r1 = r0 + 4096;                   // row lane+64
#pragma unroll
    for (int t = 0; t < 2; ++t) {
      const int sl = (((w * 2 + t) ^ sw)) * 4;     // XOR-swizzled float4 slot
      const float4 e0 = *(const float4*)&r0[sl];
      const float4 e1 = *(const float4*)&r1[sl];
      const float ev0[4] = {e0.x, e0.y, e0.z, e0.w};
      const float ev1[4] = {e1.x, e1.y, e1.z, e1.w};
      const float* wt4 = wp + t * 96;              // 4 h-cols x 24
#pragma unroll
      for (int m = 0; m < 4; ++m) {
        const float a = ev0[m], b = ev1[m];
        const float* wc = wt4 + m * 24;
#pragma unroll
        for (int j = 0; j < 24; ++j) {
          acc0[j] = fmaf(a, wc[j], acc0[j]);
          acc1[j] = fmaf(b, wc[j], acc1[j]);
        }
      }
    }
  };

  stage(0, 0);

#pragma unroll 1
  for (int ci = 0; ci < 16; ++ci) {
    const int buf = ci & 1;
    __syncthreads();                       // drains vmem: stage(ci) landed; buf^1 free
    if (ci < 15) stage(ci + 1, buf ^ 1);   // prefetch in flight across compute(ci)
    compute(ci, buf);
  }

  // epilogue: cross-wave reduce over the 8 h-slices + bias, plain stores.
  // partials layout [w][row][25] (pad 25 -> lane stride 25 floats, odd mod 32).
  __syncthreads();
  {
    float* p0 = &smem[w * 3200 + lane * 25];
    float* p1 = p0 + 64 * 25;
#pragma unroll
    for (int j = 0; j < 24; ++j) { p0[j] = acc0[j]; p1[j] = acc1[j]; }
  }
  __syncthreads();
  {
    const int row = tid >> 2, j0 = (tid & 3) * 6;
#pragma unroll
    for (int u = 0; u < 6; ++u) {
      const int j = j0 + u;
      float s = bias[j];
#pragma unroll
      for (int w8 = 0; w8 < 8; ++w8) s += smem[w8 * 3200 + row * 25 + j];
      out[1 + (size_t)(j >> 3) * (BT * 8) + (size_t)(row0 + row) * 8 + (j & 7)] = s;
    }
  }
}

// ---------- CRF v6: chunk-parallel scan (unchanged) --------------------------
__global__ __launch_bounds__(512) void crf_kernel(const int* __restrict__ labels,
                                                  const float* __restrict__ startT,
                                                  const float* __restrict__ endT,
                                                  const float* __restrict__ trans,
                                                  float* __restrict__ d_out) {
  __shared__ float sA[32 * 64];          // chunk matrices [i][p][c]
  __shared__ float sVB[32 * 8];          // vit boundary vectors
  __shared__ int   sBP[512];             // vit packed bp words
  __shared__ int   sMap[32 * 8];         // vit exit->entry maps
  __shared__ int   sEnt[32];             // vit chunk entry states
  __shared__ float sRed[32];             // fwd numerator partials
  __shared__ unsigned char sTags[512];
  __shared__ int sTerm;

  const int tid = threadIdx.x;
  const int lane = tid & 63;
  const int w = tid >> 6;
  const int c = lane & 7;
  const int p = (lane >> 3) & 7;
  const int role = (blockIdx.x >= 192);
  const int seq = role ? blockIdx.x - 192 : blockIdx.x;
  const int k = seq >> 6, b = seq & 63;
  const float* em = d_out + 1 + ((size_t)k * BT + (size_t)b * 512) * 8;
  const float* trk = trans + k * 64;
  const int* lab = labels + b * (NK * NT) + k * NT;

  float Txc[8];
#pragma unroll
  for (int kk = 0; kk < 8; ++kk) Txc[kk] = trk[(c ^ kk) * 8 + c];
  const float Tpc = trk[p * 8 + c];
  const float startc = startT[k * 8 + c];
  const float endc = endT[k * 8 + c];

  if (!role) {
    // ========================= FORWARD (logZ + loss) ========================
    float Mxc[8];
#pragma unroll
    for (int kk = 0; kk < 8; ++kk) Mxc[kk] = __expf(Txc[kk]);

    // phase 1: linear-domain chunk matrices, constant 2^-32 renorm at step 8
#pragma unroll 1
    for (int it = 0; it < 4; ++it) {
      const int i = w * 4 + it;
      const int t0 = i * 16;
      const int te = (t0 + 16 < 512) ? (t0 + 16) : 511;
      float EX[16];
      EX[0] = em[(t0 + 1) * 8 + c];             // raw em for init
#pragma unroll
      for (int j = 1; j < 16; ++j) {
        int t = t0 + 1 + j;
        EX[j] = (t <= te) ? __expf(em[t * 8 + c]) : 1.0f;
      }
      float V = __expf(Tpc + EX[0]);
#pragma unroll
      for (int j = 1; j < 16; ++j) {
        int t = t0 + 1 + j;
        if (t <= te) {
          float x1 = dppf<QP1>(V), x2 = dppf<QP2>(V), x3 = dppf<QP2>(x1);
          float x7 = dppf<HM>(V), x6 = dppf<QP1>(x7), x5 = dppf<QP2>(x7), x4 = dppf<QP2>(x6);
          float s01 = fmaf(x1, Mxc[1], V * Mxc[0]);
          float s23 = fmaf(x3, Mxc[3], x2 * Mxc[2]);
          float s45 = fmaf(x5, Mxc[5], x4 * Mxc[4]);
          float s67 = fmaf(x7, Mxc[7], x6 * Mxc[6]);
          V = ((s01 + s23) + (s45 + s67)) * EX[j];
        }
        if (j == 8) V *= 0x1p-32f;              // exact pow2 renorm (uniform)
      }
      sA[i * 64 + lane] = V;
    }
    __syncthreads();

    float logZ = 0.0f;
    if (w == 0) {
      // phase 2: 32-step alpha scan
      float al = __expf(startc + em[c]);
      float lz = 0.0f;
#pragma unroll 1
      for (int i = 0; i < 32; ++i) {
        const float* Ai = &sA[i * 64];
        float A0 = Ai[(c ^ 0) * 8 + c], A1 = Ai[(c ^ 1) * 8 + c];
        float A2 = Ai[(c ^ 2) * 8 + c], A3 = Ai[(c ^ 3) * 8 + c];
        float A4 = Ai[(c ^ 4) * 8 + c], A5 = Ai[(c ^ 5) * 8 + c];
        float A6 = Ai[(c ^ 6) * 8 + c], A7 = Ai[(c ^ 7) * 8 + c];
        float a1 = dppf<QP1>(al), a2 = dppf<QP2>(al), a3 = dppf<QP2>(a1);
        float a4 = dppf<ROR4>(al), a5 = dppf<ROR4>(a1), a6 = dppf<ROR4>(a2), a7 = dppf<ROR4>(a3);
        float s01 = fmaf(a1, A1, al * A0);
        float s23 = fmaf(a3, A3, a2 * A2);
        float s45 = fmaf(a5, A5, a4 * A4);
        float s67 = fmaf(a7, A7, a6 * A6);
        float s = (s01 + s23) + (s45 + s67);
        float ss = s;
        ss += dppf<QP1>(ss); ss += dppf<QP2>(ss); ss += dppf<ROR4>(ss);
        lz += __logf(ss);
        al = s * (1.0f / ss);
      }
      float se = al * __expf(endc);
      se += dppf<QP1>(se); se += dppf<QP2>(se); se += dppf<ROR4>(se);
      logZ = lz + __logf(se) + 1024.0f * 0.69314718055994531f;  // 32 chunks x 32 ln2
    } else {
      // phase 2 (waves 1-7): gold-path numerator
      int idx = (w - 1) * 64 + lane;            // 0..447
      float ns = 0.0f;
      {
        int tg = lab[idx];
        ns += em[(size_t)idx * 8 + tg] + trk[tg * 8 + lab[idx + 1]];
      }
      if (idx < 64) {
        int t = idx + 448;
        int tg = lab[t];
        ns += em[(size_t)t * 8 + tg];
        if (t < 511) ns += trk[tg * 8 + lab[t + 1]];
      }
      ns += dppf<QP1>(ns); ns += dppf<QP2>(ns); ns += dppf<HM>(ns); ns += dppf<ROR8>(ns);
      if ((lane & 15) == 0) sRed[(w - 1) * 4 + (lane >> 4)] = ns;
    }
    __syncthreads();
    if (tid == 0) {
      float num = startT[k * 8 + lab[0]] + endT[k * 8 + lab[511]];
#pragma unroll
      for (int u = 0; u < 28; ++u) num += sRed[u];
      atomicAdd(d_out, logZ - num);
    }
  } else {
    // ========================= VITERBI (preds) ==============================
    // phase 1: max-plus chunk matrices
#pragma unroll 1
    for (int it = 0; it < 4; ++it) {
      const int i = w * 4 + it;
      const int t0 = i * 16;
      const int te = (t0 + 16 < 512) ? (t0 + 16) : 511;
      float emv[16];
#pragma unroll
      for (int j = 0; j < 16; ++j) {
        int t = t0 + 1 + j;
        emv[j] = (t <= te) ? em[t * 8 + c] : 0.0f;
      }
      float V = Tpc + emv[0];
#pragma unroll
      for (int j = 1; j < 16; ++j) {
        int t = t0 + 1 + j;
        if (t <= te) {
          float x1 = dppf<QP1>(V), x2 = dppf<QP2>(V), x3 = dppf<QP2>(x1);
          float x7 = dppf<HM>(V), x6 = dppf<QP1>(x7), x5 = dppf<QP2>(x7), x4 = dppf<QP2>(x6);
          float c0 = V + Txc[0], c1 = x1 + Txc[1], c2 = x2 + Txc[2], c3 = x3 + Txc[3];
          float c4 = x4 + Txc[4], c5 = x5 + Txc[5], c6 = x6 + Txc[6], c7 = x7 + Txc[7];
          float m0 = fmaxf(fmaxf(c0, c1), c2);
          float m1 = fmaxf(fmaxf(c3, c4), c5);
          float m2 = fmaxf(c6, c7);
          V = fmaxf(fmaxf(m0, m1), m2) + emv[j];
        }
      }
      sA[i * 64 + lane] = V;
    }
    __syncthreads();

    // phase 2: v scan (wave 0), store boundary vectors
    if (w == 0) {
      float v = startc + em[c];
#pragma unroll 1
      for (int i = 0; i < 32; ++i) {
        if (lane < 8) sVB[i * 8 + c] = v;
        const float* Ai = &sA[i * 64];
        float A0 = Ai[(c ^ 0) * 8 + c], A1 = Ai[(c ^ 1) * 8 + c];
        float A2 = Ai[(c ^ 2) * 8 + c], A3 = Ai[(c ^ 3) * 8 + c];
        float A4 = Ai[(c ^ 4) * 8 + c], A5 = Ai[(c ^ 5) * 8 + c];
        float A6 = Ai[(c ^ 6) * 8 + c], A7 = Ai[(c ^ 7) * 8 + c];
        float a1 = dppf<QP1>(v), a2 = dppf<QP2>(v), a3 = dppf<QP2>(a1);
        float a4 = dppf<ROR4>(v), a5 = dppf<ROR4>(a1), a6 = dppf<ROR4>(a2), a7 = dppf<ROR4>(a3);
        float c0 = v + A0, c1 = a1 + A1, c2 = a2 + A2, c3 = a3 + A3;
        float c4 = a4 + A4, c5 = a5 + A5, c6 = a6 + A6, c7 = a7 + A7;
        float m0 = fmaxf(fmaxf(c0, c1), c2);
        float m1 = fmaxf(fmaxf(c3, c4), c5);
        float m2 = fmaxf(c6, c7);
        v = fmaxf(fmaxf(m0, m1), m2);
      }
      float lv = v + endc;
      int li = c;
      {
        float ov; int oi; bool take;
        ov = dppf<QP1>(lv); oi = dppi<QP1>(li);
        take = (ov > lv) || (ov == lv && oi < li); lv = take ? ov : lv; li = take ? oi : li;
        ov = dppf<QP2>(lv); oi = dppi<QP2>(li);
        take = (ov > lv) || (ov == lv && oi < li); lv = take ? ov : lv; li = take ? oi : li;
        ov = dppf<ROR4>(lv); oi = dppi<ROR4>(li);
        take = (ov > lv) || (ov == lv && oi < li); lv = take ? ov : lv; li = take ? oi : li;
      }
      if (lane == 0) sTerm = li;
    }
    __syncthreads();

    // phase 3: exact bp recompute, 8 chunk-slots per wave (waves 0-3)
    if (w < 4) {
      const int u = lane >> 3;
      const int i = w * 8 + u;
      const int t0 = i * 16;
      const int te = (t0 + 16 < 512) ? (t0 + 16) : 511;
      float emv[16];
#pragma unroll
      for (int j = 0; j < 16; ++j) {
        int t = t0 + 1 + j;
        emv[j] = (t <= te) ? em[t * 8 + c] : 0.0f;
      }
      float v = sVB[i * 8 + c];
#pragma unroll
      for (int j = 0; j < 16; ++j) {
        int t = t0 + 1 + j;
        if (t <= te) {
          float x1 = dppf<QP1>(v), x2 = dppf<QP2>(v), x3 = dppf<QP2>(x1);
          float x7 = dppf<HM>(v), x6 = dppf<QP1>(x7), x5 = dppf<QP2>(x7), x4 = dppf<QP2>(x6);
          float c0 = v + Txc[0], c1 = x1 + Txc[1], c2 = x2 + Txc[2], c3 = x3 + Txc[3];
          float c4 = x4 + Txc[4], c5 = x5 + Txc[5], c6 = x6 + Txc[6], c7 = x7 + Txc[7];
          float m0 = fmaxf(fmaxf(c0, c1), c2);
          float m1 = fmaxf(fmaxf(c3, c4), c5);
          float m2 = fmaxf(c6, c7);
          float best = fmaxf(fmaxf(m0, m1), m2);
          int a0 = (c0 == best) ? (c ^ 0) : 8;
          int a1i = (c1 == best) ? (c ^ 1) : 8;
          int a2i = (c2 == best) ? (c ^ 2) : 8;
          int a3i = (c3 == best) ? (c ^ 3) : 8;
          int a4i = (c4 == best) ? (c ^ 4) : 8;
          int a5i = (c5 == best) ? (c ^ 5) : 8;
          int a6i = (c6 == best) ? (c ^ 6) : 8;
          int a7i = (c7 == best) ? (c ^ 7) : 8;
          int arg = min(min(min(a0, a1i), min(a2i, a3i)),
                        min(min(a4i, a5i), min(a6i, a7i)));
          v = best + emv[j];
          int wd = arg << (3 * c);
          wd |= dppi<QP1>(wd); wd |= dppi<QP2>(wd); wd |= dppi<HM>(wd);
          if ((lane & 7) == 0) sBP[t] = wd;
        }
      }
    }
    __syncthreads();

    // phase 4a: per-chunk exit->entry maps (all 8 exit states in parallel)
    if (w < 4) {
      const int u = lane >> 3;
      const int i = w * 8 + u;
      const int t0 = i * 16;
      const int te = (t0 + 16 < 512) ? (t0 + 16) : 511;
      int tag = c;
#pragma unroll
      for (int j = 16; j >= 1; --j) {
        int t = t0 + j;
        if (t <= te) tag = (sBP[t] >> (3 * tag)) & 7;
      }
      sMap[i * 8 + c] = tag;
    }
    __syncthreads();
    // phase 4b: compose maps -> chunk entry states
    if (tid == 0) {
      int cur = sTerm;
#pragma unroll 1
      for (int i = 31; i >= 0; --i) { cur = sMap[i * 8 + cur]; sEnt[i] = cur; }
    }
    __syncthreads();
    // phase 4c: emit tags per chunk (32 parallel lanes)
    if (w == 0 && lane < 32) {
      const int i = lane;
      const int t0 = i * 16;
      const int te = (t0 + 16 < 512) ? (t0 + 16) : 511;
      int tag = (i == 31) ? sTerm : sEnt[i + 1];
      if (i == 31) sTags[511] = (unsigned char)tag;
#pragma unroll
      for (int j = 16; j >= 1; --j) {
        int t = t0 + j;
        if (t <= te) { tag = (sBP[t] >> (3 * tag)) & 7; sTags[t - 1] = (unsigned char)tag; }
      }
    }
    __syncthreads();
    // phase 5: coalesced pred store
    float* outp = d_out + 1 + LOGITS_N + (size_t)seq * 512;
    outp[tid] = (float)sTags[tid];
  }
}

extern "C" void kernel_launch(void* const* d_in, const int* in_sizes, int n_in,
                              void* d_out, int out_size, void* d_ws, size_t ws_size,
                              hipStream_t stream) {
  const float* enc    = (const float*)d_in[0];
  const int*   labels = (const int*)  d_in[1];
  const float* W      = (const float*)d_in[2];
  const float* bias   = (const float*)d_in[3];
  const float* startT = (const float*)d_in[4];
  const float* endT   = (const float*)d_in[5];
  const float* trans  = (const float*)d_in[6];
  float* out = (float*)d_out;
  float* Wt  = (float*)d_ws;   // 24*1024 floats = 96 KB scratch

  init_kernel<<<dim3(96), dim3(256), 0, stream>>>(W, Wt, out);
  proj_kernel<<<dim3(256), dim3(512), 0, stream>>>(enc, Wt, bias, out);
  crf_kernel<<<dim3(384), dim3(512), 0, stream>>>(labels, startT, endT, trans, out);
}

// Round 4
// 241.771 us; speedup vs baseline: 1.1283x; 1.0411x over previous
//
#include <hip/hip_runtime.h>

#define NB 64
#define NT 512
#define NH 1024
#define NC 8
#define NK 3
#define BT (NB*NT)             // 32768
#define LOGITS_N (NK*BT*NC)    // 786432

// DPP controls
#define QP1  0xB1   // quad_perm [1,0,3,2] -> lane^1
#define QP2  0x4E   // quad_perm [2,3,0,1] -> lane^2
#define ROR4 0x124  // row_ror:4  -> lane^4 (may flip bit3: only safe when value replicated across 8-groups)
#define ROR8 0x128  // row_ror:8  -> exact lane^8 within 16-row
#define HM   0x141  // row_half_mirror -> exact lane^7 within 8

template<int CTRL>
__device__ __forceinline__ float dppf(float x) {
  return __int_as_float(__builtin_amdgcn_update_dpp(0, __float_as_int(x), CTRL, 0xF, 0xF, true));
}
template<int CTRL>
__device__ __forceinline__ int dppi(int x) {
  return __builtin_amdgcn_update_dpp(0, x, CTRL, 0xF, 0xF, true);
}

__device__ __forceinline__ void gload_lds16(const float* g, float* l) {
  __builtin_amdgcn_global_load_lds(
      (const __attribute__((address_space(1))) void*)g,
      (__attribute__((address_space(3))) void*)l, 16, 0, 0);
}

// ---------- init: transpose W -> Wt[h][24], zero loss -----------------------
__global__ __launch_bounds__(256) void init_kernel(const float* __restrict__ W,
                                                   float* __restrict__ Wt,
                                                   float* __restrict__ out) {
  int i = blockIdx.x * 256 + threadIdx.x;
  if (i < 24 * NH) {
    int h = i / 24, j = i - h * 24;
    int kk = j >> 3, cc = j & 7;
    Wt[i] = W[kk * NC * NH + cc * NH + h];   // Wt[h*24 + j]
  }
  if (i == 0) out[0] = 0.0f;
}

// ---------- proj v11: WEIGHTS IN LDS (kills the SMEM serial chain) ----------
// 256 blocks x 512 thr (8 waves). Block = 128 rows x full H.
// LDS (128 KB): sW = full Wt copy (96 KB, preloaded once via global_load_lds)
//             | 2 x 16 KB encoding stage (32-col chunks, 32 of them).
// Weight access inside the loop = broadcast ds_read_b128 (uniform addr,
// conflict-free, pipelined) -> no SGPR capacity limit, no s_load latency
// chain. Encoding stage: XOR-swizzled global source + matching XOR on the
// read slot (both-sides rule); one __syncthreads per chunk (m97 pattern).
// Wave w owns h-cols ci*32+w*4..+3; lane holds acc[2][24] (rows lane,lane+64).
__global__ __launch_bounds__(512, 1) void proj_kernel(const float* __restrict__ enc,
                                                      const float* __restrict__ Wt,
                                                      const float* __restrict__ bias,
                                                      float* __restrict__ out) {
  __shared__ float smem[32768];            // 128 KB: [0,24576) sW | [24576,32768) stage
  float* const sW = smem;
  float* const sStage = smem + 24576;
  const int tid = threadIdx.x;
  const int lane = tid & 63;
  const int w = tid >> 6;                  // 8 waves
  const int row0 = blockIdx.x * 128;
  const float* eb = enc + (size_t)row0 * 1024;

  float acc0[24], acc1[24];
#pragma unroll
  for (int j = 0; j < 24; ++j) { acc0[j] = 0.0f; acc1[j] = 0.0f; }

  // ---- one-time weight preload: 96 x 1KB coalesced global_load_lds --------
#pragma unroll
  for (int i = 0; i < 12; ++i) {
    const int u = w * 12 + i;              // 0..95, wave-uniform
    gload_lds16(Wt + u * 256 + lane * 4, &sW[u * 256]);
  }

  // stage chunk ci (32 cols = 128B/row) into buf: 2 gload_lds16 per wave,
  // each = 8 rows x 128B. LDS row r linear at buf*4096 + r*32; slot s holds
  // global float4 s^(r&7) (source pre-swizzled).
  auto stage = [&](int ci, int buf) {
#pragma unroll
    for (int i = 0; i < 2; ++i) {
      const int rbase = w * 16 + i * 8;    // wave-uniform 8-row group
      const int r = rbase + (lane >> 3);
      const int s = (lane & 7) ^ (r & 7);
      gload_lds16(eb + (size_t)r * 1024 + ci * 32 + s * 4,
                  &sStage[buf * 4096 + rbase * 32]);
    }
  };

  // compute chunk ci from buf: wave w covers 4 h-cols; lane = rows {lane,lane+64}
  auto compute = [&](int ci, int buf) {
    const float* wp = &sW[(ci * 32 + w * 4) * 24];     // 96 floats, uniform
    const int sl = (w ^ (lane & 7)) * 4;               // XOR-swizzled float4 slot
    const float* r0 = &sStage[buf * 4096 + lane * 32];
    const float4 e0 = *(const float4*)&r0[sl];
    const float4 e1 = *(const float4*)&r0[64 * 32 + sl];
    const float ev0[4] = {e0.x, e0.y, e0.z, e0.w};
    const float ev1[4] = {e1.x, e1.y, e1.z, e1.w};
#pragma unroll
    for (int h = 0; h < 4; ++h) {
      const float* wh = wp + h * 24;
      float wv[24];
#pragma unroll
      for (int q = 0; q < 6; ++q) {
        const float4 t4 = *(const float4*)&wh[q * 4];
        wv[q*4+0] = t4.x; wv[q*4+1] = t4.y; wv[q*4+2] = t4.z; wv[q*4+3] = t4.w;
      }
      const float a = ev0[h], b = ev1[h];
#pragma unroll
      for (int j = 0; j < 24; ++j) {
        acc0[j] = fmaf(a, wv[j], acc0[j]);
        acc1[j] = fmaf(b, wv[j], acc1[j]);
      }
    }
  };

  stage(0, 0);
  __syncthreads();                         // weights + chunk 0 resident

#pragma unroll 1
  for (int ci = 0; ci < 32; ++ci) {
    const int buf = ci & 1;
    if (ci < 31) stage(ci + 1, buf ^ 1);   // in flight across compute(ci)
    compute(ci, buf);
    __syncthreads();                       // drains vmem; buf free next iter
  }

  // epilogue: cross-wave reduce over the 8 h-slices + bias, plain stores.
  // Reuses the whole LDS block (weights are dead). [w][row][25] padded.
  {
    float* p0 = &smem[w * 3200 + lane * 25];
    float* p1 = p0 + 64 * 25;
#pragma unroll
    for (int j = 0; j < 24; ++j) { p0[j] = acc0[j]; p1[j] = acc1[j]; }
  }
  __syncthreads();
  {
    const int row = tid >> 2, j0 = (tid & 3) * 6;
#pragma unroll
    for (int u = 0; u < 6; ++u) {
      const int j = j0 + u;
      float s = bias[j];
#pragma unroll
      for (int w8 = 0; w8 < 8; ++w8) s += smem[w8 * 3200 + row * 25 + j];
      out[1 + (size_t)(j >> 3) * (BT * 8) + (size_t)(row0 + row) * 8 + (j & 7)] = s;
    }
  }
}

// ---------- CRF v6: chunk-parallel scan (unchanged) --------------------------
__global__ __launch_bounds__(512) void crf_kernel(const int* __restrict__ labels,
                                                  const float* __restrict__ startT,
                                                  const float* __restrict__ endT,
                                                  const float* __restrict__ trans,
                                                  float* __restrict__ d_out) {
  __shared__ float sA[32 * 64];          // chunk matrices [i][p][c]
  __shared__ float sVB[32 * 8];          // vit boundary vectors
  __shared__ int   sBP[512];             // vit packed bp words
  __shared__ int   sMap[32 * 8];         // vit exit->entry maps
  __shared__ int   sEnt[32];             // vit chunk entry states
  __shared__ float sRed[32];             // fwd numerator partials
  __shared__ unsigned char sTags[512];
  __shared__ int sTerm;

  const int tid = threadIdx.x;
  const int lane = tid & 63;
  const int w = tid >> 6;
  const int c = lane & 7;
  const int p = (lane >> 3) & 7;
  const int role = (blockIdx.x >= 192);
  const int seq = role ? blockIdx.x - 192 : blockIdx.x;
  const int k = seq >> 6, b = seq & 63;
  const float* em = d_out + 1 + ((size_t)k * BT + (size_t)b * 512) * 8;
  const float* trk = trans + k * 64;
  const int* lab = labels + b * (NK * NT) + k * NT;

  float Txc[8];
#pragma unroll
  for (int kk = 0; kk < 8; ++kk) Txc[kk] = trk[(c ^ kk) * 8 + c];
  const float Tpc = trk[p * 8 + c];
  const float startc = startT[k * 8 + c];
  const float endc = endT[k * 8 + c];

  if (!role) {
    // ========================= FORWARD (logZ + loss) ========================
    float Mxc[8];
#pragma unroll
    for (int kk = 0; kk < 8; ++kk) Mxc[kk] = __expf(Txc[kk]);

    // phase 1: linear-domain chunk matrices, constant 2^-32 renorm at step 8
#pragma unroll 1
    for (int it = 0; it < 4; ++it) {
      const int i = w * 4 + it;
      const int t0 = i * 16;
      const int te = (t0 + 16 < 512) ? (t0 + 16) : 511;
      float EX[16];
      EX[0] = em[(t0 + 1) * 8 + c];             // raw em for init
#pragma unroll
      for (int j = 1; j < 16; ++j) {
        int t = t0 + 1 + j;
        EX[j] = (t <= te) ? __expf(em[t * 8 + c]) : 1.0f;
      }
      float V = __expf(Tpc + EX[0]);
#pragma unroll
      for (int j = 1; j < 16; ++j) {
        int t = t0 + 1 + j;
        if (t <= te) {
          float x1 = dppf<QP1>(V), x2 = dppf<QP2>(V), x3 = dppf<QP2>(x1);
          float x7 = dppf<HM>(V), x6 = dppf<QP1>(x7), x5 = dppf<QP2>(x7), x4 = dppf<QP2>(x6);
          float s01 = fmaf(x1, Mxc[1], V * Mxc[0]);
          float s23 = fmaf(x3, Mxc[3], x2 * Mxc[2]);
          float s45 = fmaf(x5, Mxc[5], x4 * Mxc[4]);
          float s67 = fmaf(x7, Mxc[7], x6 * Mxc[6]);
          V = ((s01 + s23) + (s45 + s67)) * EX[j];
        }
        if (j == 8) V *= 0x1p-32f;              // exact pow2 renorm (uniform)
      }
      sA[i * 64 + lane] = V;
    }
    __syncthreads();

    float logZ = 0.0f;
    if (w == 0) {
      // phase 2: 32-step alpha scan
      float al = __expf(startc + em[c]);
      float lz = 0.0f;
#pragma unroll 1
      for (int i = 0; i < 32; ++i) {
        const float* Ai = &sA[i * 64];
        float A0 = Ai[(c ^ 0) * 8 + c], A1 = Ai[(c ^ 1) * 8 + c];
        float A2 = Ai[(c ^ 2) * 8 + c], A3 = Ai[(c ^ 3) * 8 + c];
        float A4 = Ai[(c ^ 4) * 8 + c], A5 = Ai[(c ^ 5) * 8 + c];
        float A6 = Ai[(c ^ 6) * 8 + c], A7 = Ai[(c ^ 7) * 8 + c];
        float a1 = dppf<QP1>(al), a2 = dppf<QP2>(al), a3 = dppf<QP2>(a1);
        float a4 = dppf<ROR4>(al), a5 = dppf<ROR4>(a1), a6 = dppf<ROR4>(a2), a7 = dppf<ROR4>(a3);
        float s01 = fmaf(a1, A1, al * A0);
        float s23 = fmaf(a3, A3, a2 * A2);
        float s45 = fmaf(a5, A5, a4 * A4);
        float s67 = fmaf(a7, A7, a6 * A6);
        float s = (s01 + s23) + (s45 + s67);
        float ss = s;
        ss += dppf<QP1>(ss); ss += dppf<QP2>(ss); ss += dppf<ROR4>(ss);
        lz += __logf(ss);
        al = s * (1.0f / ss);
      }
      float se = al * __expf(endc);
      se += dppf<QP1>(se); se += dppf<QP2>(se); se += dppf<ROR4>(se);
      logZ = lz + __logf(se) + 1024.0f * 0.69314718055994531f;  // 32 chunks x 32 ln2
    } else {
      // phase 2 (waves 1-7): gold-path numerator
      int idx = (w - 1) * 64 + lane;            // 0..447
      float ns = 0.0f;
      {
        int tg = lab[idx];
        ns += em[(size_t)idx * 8 + tg] + trk[tg * 8 + lab[idx + 1]];
      }
      if (idx < 64) {
        int t = idx + 448;
        int tg = lab[t];
        ns += em[(size_t)t * 8 + tg];
        if (t < 511) ns += trk[tg * 8 + lab[t + 1]];
      }
      ns += dppf<QP1>(ns); ns += dppf<QP2>(ns); ns += dppf<HM>(ns); ns += dppf<ROR8>(ns);
      if ((lane & 15) == 0) sRed[(w - 1) * 4 + (lane >> 4)] = ns;
    }
    __syncthreads();
    if (tid == 0) {
      float num = startT[k * 8 + lab[0]] + endT[k * 8 + lab[511]];
#pragma unroll
      for (int u = 0; u < 28; ++u) num += sRed[u];
      atomicAdd(d_out, logZ - num);
    }
  } else {
    // ========================= VITERBI (preds) ==============================
    // phase 1: max-plus chunk matrices
#pragma unroll 1
    for (int it = 0; it < 4; ++it) {
      const int i = w * 4 + it;
      const int t0 = i * 16;
      const int te = (t0 + 16 < 512) ? (t0 + 16) : 511;
      float emv[16];
#pragma unroll
      for (int j = 0; j < 16; ++j) {
        int t = t0 + 1 + j;
        emv[j] = (t <= te) ? em[t * 8 + c] : 0.0f;
      }
      float V = Tpc + emv[0];
#pragma unroll
      for (int j = 1; j < 16; ++j) {
        int t = t0 + 1 + j;
        if (t <= te) {
          float x1 = dppf<QP1>(V), x2 = dppf<QP2>(V), x3 = dppf<QP2>(x1);
          float x7 = dppf<HM>(V), x6 = dppf<QP1>(x7), x5 = dppf<QP2>(x7), x4 = dppf<QP2>(x6);
          float c0 = V + Txc[0], c1 = x1 + Txc[1], c2 = x2 + Txc[2], c3 = x3 + Txc[3];
          float c4 = x4 + Txc[4], c5 = x5 + Txc[5], c6 = x6 + Txc[6], c7 = x7 + Txc[7];
          float m0 = fmaxf(fmaxf(c0, c1), c2);
          float m1 = fmaxf(fmaxf(c3, c4), c5);
          float m2 = fmaxf(c6, c7);
          V = fmaxf(fmaxf(m0, m1), m2) + emv[j];
        }
      }
      sA[i * 64 + lane] = V;
    }
    __syncthreads();

    // phase 2: v scan (wave 0), store boundary vectors
    if (w == 0) {
      float v = startc + em[c];
#pragma unroll 1
      for (int i = 0; i < 32; ++i) {
        if (lane < 8) sVB[i * 8 + c] = v;
        const float* Ai = &sA[i * 64];
        float A0 = Ai[(c ^ 0) * 8 + c], A1 = Ai[(c ^ 1) * 8 + c];
        float A2 = Ai[(c ^ 2) * 8 + c], A3 = Ai[(c ^ 3) * 8 + c];
        float A4 = Ai[(c ^ 4) * 8 + c], A5 = Ai[(c ^ 5) * 8 + c];
        float A6 = Ai[(c ^ 6) * 8 + c], A7 = Ai[(c ^ 7) * 8 + c];
        float a1 = dppf<QP1>(v), a2 = dppf<QP2>(v), a3 = dppf<QP2>(a1);
        float a4 = dppf<ROR4>(v), a5 = dppf<ROR4>(a1), a6 = dppf<ROR4>(a2), a7 = dppf<ROR4>(a3);
        float c0 = v + A0, c1 = a1 + A1, c2 = a2 + A2, c3 = a3 + A3;
        float c4 = a4 + A4, c5 = a5 + A5, c6 = a6 + A6, c7 = a7 + A7;
        float m0 = fmaxf(fmaxf(c0, c1), c2);
        float m1 = fmaxf(fmaxf(c3, c4), c5);
        float m2 = fmaxf(c6, c7);
        v = fmaxf(fmaxf(m0, m1), m2);
      }
      float lv = v + endc;
      int li = c;
      {
        float ov; int oi; bool take;
        ov = dppf<QP1>(lv); oi = dppi<QP1>(li);
        take = (ov > lv) || (ov == lv && oi < li); lv = take ? ov : lv; li = take ? oi : li;
        ov = dppf<QP2>(lv); oi = dppi<QP2>(li);
        take = (ov > lv) || (ov == lv && oi < li); lv = take ? ov : lv; li = take ? oi : li;
        ov = dppf<ROR4>(lv); oi = dppi<ROR4>(li);
        take = (ov > lv) || (ov == lv && oi < li); lv = take ? ov : lv; li = take ? oi : li;
      }
      if (lane == 0) sTerm = li;
    }
    __syncthreads();

    // phase 3: exact bp recompute, 8 chunk-slots per wave (waves 0-3)
    if (w < 4) {
      const int u = lane >> 3;
      const int i = w * 8 + u;
      const int t0 = i * 16;
      const int te = (t0 + 16 < 512) ? (t0 + 16) : 511;
      float emv[16];
#pragma unroll
      for (int j = 0; j < 16; ++j) {
        int t = t0 + 1 + j;
        emv[j] = (t <= te) ? em[t * 8 + c] : 0.0f;
      }
      float v = sVB[i * 8 + c];
#pragma unroll
      for (int j = 0; j < 16; ++j) {
        int t = t0 + 1 + j;
        if (t <= te) {
          float x1 = dppf<QP1>(v), x2 = dppf<QP2>(v), x3 = dppf<QP2>(x1);
          float x7 = dppf<HM>(v), x6 = dppf<QP1>(x7), x5 = dppf<QP2>(x7), x4 = dppf<QP2>(x6);
          float c0 = v + Txc[0], c1 = x1 + Txc[1], c2 = x2 + Txc[2], c3 = x3 + Txc[3];
          float c4 = x4 + Txc[4], c5 = x5 + Txc[5], c6 = x6 + Txc[6], c7 = x7 + Txc[7];
          float m0 = fmaxf(fmaxf(c0, c1), c2);
          float m1 = fmaxf(fmaxf(c3, c4), c5);
          float m2 = fmaxf(c6, c7);
          float best = fmaxf(fmaxf(m0, m1), m2);
          int a0 = (c0 == best) ? (c ^ 0) : 8;
          int a1i = (c1 == best) ? (c ^ 1) : 8;
          int a2i = (c2 == best) ? (c ^ 2) : 8;
          int a3i = (c3 == best) ? (c ^ 3) : 8;
          int a4i = (c4 == best) ? (c ^ 4) : 8;
          int a5i = (c5 == best) ? (c ^ 5) : 8;
          int a6i = (c6 == best) ? (c ^ 6) : 8;
          int a7i = (c7 == best) ? (c ^ 7) : 8;
          int arg = min(min(min(a0, a1i), min(a2i, a3i)),
                        min(min(a4i, a5i), min(a6i, a7i)));
          v = best + emv[j];
          int wd = arg << (3 * c);
          wd |= dppi<QP1>(wd); wd |= dppi<QP2>(wd); wd |= dppi<HM>(wd);
          if ((lane & 7) == 0) sBP[t] = wd;
        }
      }
    }
    __syncthreads();

    // phase 4a: per-chunk exit->entry maps (all 8 exit states in parallel)
    if (w < 4) {
      const int u = lane >> 3;
      const int i = w * 8 + u;
      const int t0 = i * 16;
      const int te = (t0 + 16 < 512) ? (t0 + 16) : 511;
      int tag = c;
#pragma unroll
      for (int j = 16; j >= 1; --j) {
        int t = t0 + j;
        if (t <= te) tag = (sBP[t] >> (3 * tag)) & 7;
      }
      sMap[i * 8 + c] = tag;
    }
    __syncthreads();
    // phase 4b: compose maps -> chunk entry states
    if (tid == 0) {
      int cur = sTerm;
#pragma unroll 1
      for (int i = 31; i >= 0; --i) { cur = sMap[i * 8 + cur]; sEnt[i] = cur; }
    }
    __syncthreads();
    // phase 4c: emit tags per chunk (32 parallel lanes)
    if (w == 0 && lane < 32) {
      const int i = lane;
      const int t0 = i * 16;
      const int te = (t0 + 16 < 512) ? (t0 + 16) : 511;
      int tag = (i == 31) ? sTerm : sEnt[i + 1];
      if (i == 31) sTags[511] = (unsigned char)tag;
#pragma unroll
      for (int j = 16; j >= 1; --j) {
        int t = t0 + j;
        if (t <= te) { tag = (sBP[t] >> (3 * tag)) & 7; sTags[t - 1] = (unsigned char)tag; }
      }
    }
    __syncthreads();
    // phase 5: coalesced pred store
    float* outp = d_out + 1 + LOGITS_N + (size_t)seq * 512;
    outp[tid] = (float)sTags[tid];
  }
}

extern "C" void kernel_launch(void* const* d_in, const int* in_sizes, int n_in,
                              void* d_out, int out_size, void* d_ws, size_t ws_size,
                              hipStream_t stream) {
  const float* enc    = (const float*)d_in[0];
  const int*   labels = (const int*)  d_in[1];
  const float* W      = (const float*)d_in[2];
  const float* bias   = (const float*)d_in[3];
  const float* startT = (const float*)d_in[4];
  const float* endT   = (const float*)d_in[5];
  const float* trans  = (const float*)d_in[6];
  float* out = (float*)d_out;
  float* Wt  = (float*)d_ws;   // 24*1024 floats = 96 KB scratch

  init_kernel<<<dim3(96), dim3(256), 0, stream>>>(W, Wt, out);
  proj_kernel<<<dim3(256), dim3(512), 0, stream>>>(enc, Wt, bias, out);
  crf_kernel<<<dim3(384), dim3(512), 0, stream>>>(labels, startT, endT, trans, out);
}

// Round 5
// 238.777 us; speedup vs baseline: 1.1425x; 1.0125x over previous
//
#include <hip/hip_runtime.h>

#define NB 64
#define NT 512
#define NH 1024
#define NC 8
#define NK 3
#define BT (NB*NT)             // 32768
#define LOGITS_N (NK*BT*NC)    // 786432

typedef unsigned short ushort;
typedef unsigned int uint;
typedef __attribute__((ext_vector_type(8))) short short8v;
typedef __attribute__((ext_vector_type(4))) float float4v;
union S8 { short8v v; ushort u[8]; };

// DPP controls
#define QP1  0xB1   // quad_perm [1,0,3,2] -> lane^1
#define QP2  0x4E   // quad_perm [2,3,0,1] -> lane^2
#define ROR4 0x124  // row_ror:4  -> lane^4 (value must be 8-group replicated)
#define ROR8 0x128  // row_ror:8  -> exact lane^8 within 16-row
#define HM   0x141  // row_half_mirror -> exact lane^7 within 8

template<int CTRL>
__device__ __forceinline__ float dppf(float x) {
  return __int_as_float(__builtin_amdgcn_update_dpp(0, __float_as_int(x), CTRL, 0xF, 0xF, true));
}
template<int CTRL>
__device__ __forceinline__ int dppi(int x) {
  return __builtin_amdgcn_update_dpp(0, x, CTRL, 0xF, 0xF, true);
}

__device__ __forceinline__ void gload_lds16(const void* g, void* l) {
  __builtin_amdgcn_global_load_lds(
      (const __attribute__((address_space(1))) void*)g,
      (__attribute__((address_space(3))) void*)l, 16, 0, 0);
}

// ---------- init: W -> frag-ready 3-way bf16 split WB[3][16ci][4q][64l][8] --
// Array a (a=0,1,2) holds the a-th truncation-split bf16 of W.
// Element (ci,q,l,i): kkb=q>>1, jt=q&1; k = ci*64 + kkb*32 + (l>>4)*8 + i;
// j = jt*16 + (l&15); value = (j<24) ? W[j>>3][j&7][k] : 0.
__global__ __launch_bounds__(256) void init_kernel(const float* __restrict__ W,
                                                   ushort* __restrict__ WB,
                                                   float* __restrict__ out) {
  const int i = blockIdx.x * 256 + threadIdx.x;   // 0..32767
  const int ci = i >> 11;
  const int rem = i & 2047;
  const int q = rem >> 9;
  const int l = (rem >> 3) & 63;
  const int e = i & 7;
  const int k = ci * 64 + (q >> 1) * 32 + ((l >> 4) << 3) + e;
  const int j = (q & 1) * 16 + (l & 15);
  float v = 0.0f;
  if (j < 24) v = W[(j >> 3) * (NC * NH) + (j & 7) * NH + k];
  const uint b = __float_as_uint(v);
  const ushort h1 = (ushort)(b >> 16);
  const float f1 = __uint_as_float(b & 0xFFFF0000u);
  const float r1 = v - f1;
  const uint b2 = __float_as_uint(r1);
  const ushort h2 = (ushort)(b2 >> 16);
  const float f2 = __uint_as_float(b2 & 0xFFFF0000u);
  const float r2 = r1 - f2;
  const ushort h3 = (ushort)(__float_as_uint(r2) >> 16);
  WB[i] = h1;
  WB[32768 + i] = h2;
  WB[65536 + i] = h3;
  if (i == 0) out[0] = 0.0f;
}

// ---------- proj v12: MFMA 16x16x32 bf16, 3+3 Dekker split ------------------
// 256 blocks x 512 thr (8 waves). Block = 128 rows x full K=1024; 16 chunks
// of K=64. Wave w owns rows w*16..+15 x ALL 24 cols (no cross-wave reduce).
// LDS: sA = 2 x 32KB fp32 A-stage (slot-XOR-swizzled, v11 pattern);
//      sB = 2 x 12KB frag-ready bf16 weights (lane-linear, no swizzle needed).
// A split into 3 bf16 at frag-load; B pre-split by init. 6 MFMA terms per
// (kkb,jt): a1w1,a2w1,a1w2,a2w2,a3w1,a1w3 -> logits ~1e-6 of fp32.
// C/D: col=lane&15, row=(lane>>4)*4+reg (m89-verified).
__global__ __launch_bounds__(512, 2) void proj_kernel(const float* __restrict__ enc,
                                                      const ushort* __restrict__ WB,
                                                      const float* __restrict__ bias,
                                                      float* __restrict__ out) {
  __shared__ float  sA[2][8192];    // 64 KB
  __shared__ ushort sB[2][6144];    // 24 KB
  const int tid = threadIdx.x;
  const int lane = tid & 63;
  const int w = tid >> 6;
  const int row0 = blockIdx.x * 128;
  const float* eb = enc + (size_t)row0 * 1024;

  float4v acc0 = {0.0f, 0.0f, 0.0f, 0.0f};
  float4v acc1 = {0.0f, 0.0f, 0.0f, 0.0f};

  // stage A chunk: 4 rows per instr (1 KB), source slot pre-swizzled ^(r&15)
  auto stageA = [&](int ci, int buf) {
#pragma unroll
    for (int i = 0; i < 4; ++i) {
      const int rbase = w * 16 + i * 4;
      const int r = rbase + (lane >> 4);
      const int s = (lane & 15) ^ (r & 15);
      gload_lds16(eb + (size_t)r * 1024 + ci * 64 + s * 4, &sA[buf][rbase * 64]);
    }
  };
  // stage B chunk: 12 x 1KB lane-linear (frag-ready layout, no swizzle)
  auto stageB = [&](int ci, int buf) {
    {
      const int u = w;
      gload_lds16(WB + (u >> 2) * 32768 + ci * 2048 + (u & 3) * 512 + lane * 8,
                  &sB[buf][u * 512]);
    }
    if (w < 4) {
      const int u = 8 + w;
      gload_lds16(WB + (u >> 2) * 32768 + ci * 2048 + (u & 3) * 512 + lane * 8,
                  &sB[buf][u * 512]);
    }
  };

  auto compute = [&](int buf) {
    const float* ar = &sA[buf][(w * 16 + (lane & 15)) * 64];
    const ushort* sBf = &sB[buf][0];
    const int rx = lane & 15;
    const int g = lane >> 4;
#pragma unroll
    for (int kkb = 0; kkb < 2; ++kkb) {
      const int s0 = kkb * 8 + g * 2;
      const float4 e0 = *(const float4*)&ar[(s0 ^ rx) * 4];
      const float4 e1 = *(const float4*)&ar[((s0 + 1) ^ rx) * 4];
      S8 a1, a2, a3;
      const float vals[8] = {e0.x, e0.y, e0.z, e0.w, e1.x, e1.y, e1.z, e1.w};
#pragma unroll
      for (int t = 0; t < 8; ++t) {
        const float v = vals[t];
        const uint b = __float_as_uint(v);
        a1.u[t] = (ushort)(b >> 16);
        const float f1 = __uint_as_float(b & 0xFFFF0000u);
        const float r1 = v - f1;
        const uint b2 = __float_as_uint(r1);
        a2.u[t] = (ushort)(b2 >> 16);
        const float f2 = __uint_as_float(b2 & 0xFFFF0000u);
        const float r2 = r1 - f2;
        a3.u[t] = (ushort)(__float_as_uint(r2) >> 16);
      }
#pragma unroll
      for (int jt = 0; jt < 2; ++jt) {
        const int q = kkb * 2 + jt;
        const short8v w1 = *(const short8v*)&sBf[0 * 2048 + q * 512 + lane * 8];
        const short8v w2 = *(const short8v*)&sBf[1 * 2048 + q * 512 + lane * 8];
        const short8v w3 = *(const short8v*)&sBf[2 * 2048 + q * 512 + lane * 8];
        float4v acc = jt ? acc1 : acc0;
        acc = __builtin_amdgcn_mfma_f32_16x16x32_bf16(a1.v, w1, acc, 0, 0, 0);
        acc = __builtin_amdgcn_mfma_f32_16x16x32_bf16(a2.v, w1, acc, 0, 0, 0);
        acc = __builtin_amdgcn_mfma_f32_16x16x32_bf16(a1.v, w2, acc, 0, 0, 0);
        acc = __builtin_amdgcn_mfma_f32_16x16x32_bf16(a2.v, w2, acc, 0, 0, 0);
        acc = __builtin_amdgcn_mfma_f32_16x16x32_bf16(a3.v, w1, acc, 0, 0, 0);
        acc = __builtin_amdgcn_mfma_f32_16x16x32_bf16(a1.v, w3, acc, 0, 0, 0);
        if (jt) acc1 = acc; else acc0 = acc;
      }
    }
  };

  stageA(0, 0);
  stageB(0, 0);
  __syncthreads();                         // vmcnt(0) drain: chunk 0 resident

#pragma unroll 1
  for (int ci = 0; ci < 16; ++ci) {
    const int buf = ci & 1;
    if (ci < 15) { stageA(ci + 1, buf ^ 1); stageB(ci + 1, buf ^ 1); }
    compute(buf);
    __syncthreads();                       // drains prefetch; buf free next iter
  }

  // epilogue: direct stores from MFMA C/D layout (+bias); no LDS reduce.
  const int g = lane >> 4, cx = lane & 15;
#pragma unroll
  for (int jt = 0; jt < 2; ++jt) {
    const int j = jt * 16 + cx;
    if (j < 24) {
      const float bj = bias[j];
      const float4v acc = jt ? acc1 : acc0;
      float* ob = out + 1 + (size_t)(j >> 3) * (BT * 8) + (j & 7);
#pragma unroll
      for (int qq = 0; qq < 4; ++qq) {
        const int grow = row0 + w * 16 + g * 4 + qq;
        ob[(size_t)grow * 8] = acc[qq] + bj;
      }
    }
  }
}

// ---------- CRF v6: chunk-parallel scan (unchanged) --------------------------
__global__ __launch_bounds__(512) void crf_kernel(const int* __restrict__ labels,
                                                  const float* __restrict__ startT,
                                                  const float* __restrict__ endT,
                                                  const float* __restrict__ trans,
                                                  float* __restrict__ d_out) {
  __shared__ float sA[32 * 64];          // chunk matrices [i][p][c]
  __shared__ float sVB[32 * 8];          // vit boundary vectors
  __shared__ int   sBP[512];             // vit packed bp words
  __shared__ int   sMap[32 * 8];         // vit exit->entry maps
  __shared__ int   sEnt[32];             // vit chunk entry states
  __shared__ float sRed[32];             // fwd numerator partials
  __shared__ unsigned char sTags[512];
  __shared__ int sTerm;

  const int tid = threadIdx.x;
  const int lane = tid & 63;
  const int w = tid >> 6;
  const int c = lane & 7;
  const int p = (lane >> 3) & 7;
  const int role = (blockIdx.x >= 192);
  const int seq = role ? blockIdx.x - 192 : blockIdx.x;
  const int k = seq >> 6, b = seq & 63;
  const float* em = d_out + 1 + ((size_t)k * BT + (size_t)b * 512) * 8;
  const float* trk = trans + k * 64;
  const int* lab = labels + b * (NK * NT) + k * NT;

  float Txc[8];
#pragma unroll
  for (int kk = 0; kk < 8; ++kk) Txc[kk] = trk[(c ^ kk) * 8 + c];
  const float Tpc = trk[p * 8 + c];
  const float startc = startT[k * 8 + c];
  const float endc = endT[k * 8 + c];

  if (!role) {
    // ========================= FORWARD (logZ + loss) ========================
    float Mxc[8];
#pragma unroll
    for (int kk = 0; kk < 8; ++kk) Mxc[kk] = __expf(Txc[kk]);

    // phase 1: linear-domain chunk matrices, constant 2^-32 renorm at step 8
#pragma unroll 1
    for (int it = 0; it < 4; ++it) {
      const int i = w * 4 + it;
      const int t0 = i * 16;
      const int te = (t0 + 16 < 512) ? (t0 + 16) : 511;
      float EX[16];
      EX[0] = em[(t0 + 1) * 8 + c];             // raw em for init
#pragma unroll
      for (int j = 1; j < 16; ++j) {
        int t = t0 + 1 + j;
        EX[j] = (t <= te) ? __expf(em[t * 8 + c]) : 1.0f;
      }
      float V = __expf(Tpc + EX[0]);
#pragma unroll
      for (int j = 1; j < 16; ++j) {
        int t = t0 + 1 + j;
        if (t <= te) {
          float x1 = dppf<QP1>(V), x2 = dppf<QP2>(V), x3 = dppf<QP2>(x1);
          float x7 = dppf<HM>(V), x6 = dppf<QP1>(x7), x5 = dppf<QP2>(x7), x4 = dppf<QP2>(x6);
          float s01 = fmaf(x1, Mxc[1], V * Mxc[0]);
          float s23 = fmaf(x3, Mxc[3], x2 * Mxc[2]);
          float s45 = fmaf(x5, Mxc[5], x4 * Mxc[4]);
          float s67 = fmaf(x7, Mxc[7], x6 * Mxc[6]);
          V = ((s01 + s23) + (s45 + s67)) * EX[j];
        }
        if (j == 8) V *= 0x1p-32f;              // exact pow2 renorm (uniform)
      }
      sA[i * 64 + lane] = V;
    }
    __syncthreads();

    float logZ = 0.0f;
    if (w == 0) {
      // phase 2: 32-step alpha scan
      float al = __expf(startc + em[c]);
      float lz = 0.0f;
#pragma unroll 1
      for (int i = 0; i < 32; ++i) {
        const float* Ai = &sA[i * 64];
        float A0 = Ai[(c ^ 0) * 8 + c], A1 = Ai[(c ^ 1) * 8 + c];
        float A2 = Ai[(c ^ 2) * 8 + c], A3 = Ai[(c ^ 3) * 8 + c];
        float A4 = Ai[(c ^ 4) * 8 + c], A5 = Ai[(c ^ 5) * 8 + c];
        float A6 = Ai[(c ^ 6) * 8 + c], A7 = Ai[(c ^ 7) * 8 + c];
        float a1 = dppf<QP1>(al), a2 = dppf<QP2>(al), a3 = dppf<QP2>(a1);
        float a4 = dppf<ROR4>(al), a5 = dppf<ROR4>(a1), a6 = dppf<ROR4>(a2), a7 = dppf<ROR4>(a3);
        float s01 = fmaf(a1, A1, al * A0);
        float s23 = fmaf(a3, A3, a2 * A2);
        float s45 = fmaf(a5, A5, a4 * A4);
        float s67 = fmaf(a7, A7, a6 * A6);
        float s = (s01 + s23) + (s45 + s67);
        float ss = s;
        ss += dppf<QP1>(ss); ss += dppf<QP2>(ss); ss += dppf<ROR4>(ss);
        lz += __logf(ss);
        al = s * (1.0f / ss);
      }
      float se = al * __expf(endc);
      se += dppf<QP1>(se); se += dppf<QP2>(se); se += dppf<ROR4>(se);
      logZ = lz + __logf(se) + 1024.0f * 0.69314718055994531f;  // 32 chunks x 32 ln2
    } else {
      // phase 2 (waves 1-7): gold-path numerator
      int idx = (w - 1) * 64 + lane;            // 0..447
      float ns = 0.0f;
      {
        int tg = lab[idx];
        ns += em[(size_t)idx * 8 + tg] + trk[tg * 8 + lab[idx + 1]];
      }
      if (idx < 64) {
        int t = idx + 448;
        int tg = lab[t];
        ns += em[(size_t)t * 8 + tg];
        if (t < 511) ns += trk[tg * 8 + lab[t + 1]];
      }
      ns += dppf<QP1>(ns); ns += dppf<QP2>(ns); ns += dppf<HM>(ns); ns += dppf<ROR8>(ns);
      if ((lane & 15) == 0) sRed[(w - 1) * 4 + (lane >> 4)] = ns;
    }
    __syncthreads();
    if (tid == 0) {
      float num = startT[k * 8 + lab[0]] + endT[k * 8 + lab[511]];
#pragma unroll
      for (int u = 0; u < 28; ++u) num += sRed[u];
      atomicAdd(d_out, logZ - num);
    }
  } else {
    // ========================= VITERBI (preds) ==============================
    // phase 1: max-plus chunk matrices
#pragma unroll 1
    for (int it = 0; it < 4; ++it) {
      const int i = w * 4 + it;
      const int t0 = i * 16;
      const int te = (t0 + 16 < 512) ? (t0 + 16) : 511;
      float emv[16];
#pragma unroll
      for (int j = 0; j < 16; ++j) {
        int t = t0 + 1 + j;
        emv[j] = (t <= te) ? em[t * 8 + c] : 0.0f;
      }
      float V = Tpc + emv[0];
#pragma unroll
      for (int j = 1; j < 16; ++j) {
        int t = t0 + 1 + j;
        if (t <= te) {
          float x1 = dppf<QP1>(V), x2 = dppf<QP2>(V), x3 = dppf<QP2>(x1);
          float x7 = dppf<HM>(V), x6 = dppf<QP1>(x7), x5 = dppf<QP2>(x7), x4 = dppf<QP2>(x6);
          float c0 = V + Txc[0], c1 = x1 + Txc[1], c2 = x2 + Txc[2], c3 = x3 + Txc[3];
          float c4 = x4 + Txc[4], c5 = x5 + Txc[5], c6 = x6 + Txc[6], c7 = x7 + Txc[7];
          float m0 = fmaxf(fmaxf(c0, c1), c2);
          float m1 = fmaxf(fmaxf(c3, c4), c5);
          float m2 = fmaxf(c6, c7);
          V = fmaxf(fmaxf(m0, m1), m2) + emv[j];
        }
      }
      sA[i * 64 + lane] = V;
    }
    __syncthreads();

    // phase 2: v scan (wave 0), store boundary vectors
    if (w == 0) {
      float v = startc + em[c];
#pragma unroll 1
      for (int i = 0; i < 32; ++i) {
        if (lane < 8) sVB[i * 8 + c] = v;
        const float* Ai = &sA[i * 64];
        float A0 = Ai[(c ^ 0) * 8 + c], A1 = Ai[(c ^ 1) * 8 + c];
        float A2 = Ai[(c ^ 2) * 8 + c], A3 = Ai[(c ^ 3) * 8 + c];
        float A4 = Ai[(c ^ 4) * 8 + c], A5 = Ai[(c ^ 5) * 8 + c];
        float A6 = Ai[(c ^ 6) * 8 + c], A7 = Ai[(c ^ 7) * 8 + c];
        float a1 = dppf<QP1>(v), a2 = dppf<QP2>(v), a3 = dppf<QP2>(a1);
        float a4 = dppf<ROR4>(v), a5 = dppf<ROR4>(a1), a6 = dppf<ROR4>(a2), a7 = dppf<ROR4>(a3);
        float c0 = v + A0, c1 = a1 + A1, c2 = a2 + A2, c3 = a3 + A3;
        float c4 = a4 + A4, c5 = a5 + A5, c6 = a6 + A6, c7 = a7 + A7;
        float m0 = fmaxf(fmaxf(c0, c1), c2);
        float m1 = fmaxf(fmaxf(c3, c4), c5);
        float m2 = fmaxf(c6, c7);
        v = fmaxf(fmaxf(m0, m1), m2);
      }
      float lv = v + endc;
      int li = c;
      {
        float ov; int oi; bool take;
        ov = dppf<QP1>(lv); oi = dppi<QP1>(li);
        take = (ov > lv) || (ov == lv && oi < li); lv = take ? ov : lv; li = take ? oi : li;
        ov = dppf<QP2>(lv); oi = dppi<QP2>(li);
        take = (ov > lv) || (ov == lv && oi < li); lv = take ? ov : lv; li = take ? oi : li;
        ov = dppf<ROR4>(lv); oi = dppi<ROR4>(li);
        take = (ov > lv) || (ov == lv && oi < li); lv = take ? ov : lv; li = take ? oi : li;
      }
      if (lane == 0) sTerm = li;
    }
    __syncthreads();

    // phase 3: exact bp recompute, 8 chunk-slots per wave (waves 0-3)
    if (w < 4) {
      const int u = lane >> 3;
      const int i = w * 8 + u;
      const int t0 = i * 16;
      const int te = (t0 + 16 < 512) ? (t0 + 16) : 511;
      float emv[16];
#pragma unroll
      for (int j = 0; j < 16; ++j) {
        int t = t0 + 1 + j;
        emv[j] = (t <= te) ? em[t * 8 + c] : 0.0f;
      }
      float v = sVB[i * 8 + c];
#pragma unroll
      for (int j = 0; j < 16; ++j) {
        int t = t0 + 1 + j;
        if (t <= te) {
          float x1 = dppf<QP1>(v), x2 = dppf<QP2>(v), x3 = dppf<QP2>(x1);
          float x7 = dppf<HM>(v), x6 = dppf<QP1>(x7), x5 = dppf<QP2>(x7), x4 = dppf<QP2>(x6);
          float c0 = v + Txc[0], c1 = x1 + Txc[1], c2 = x2 + Txc[2], c3 = x3 + Txc[3];
          float c4 = x4 + Txc[4], c5 = x5 + Txc[5], c6 = x6 + Txc[6], c7 = x7 + Txc[7];
          float m0 = fmaxf(fmaxf(c0, c1), c2);
          float m1 = fmaxf(fmaxf(c3, c4), c5);
          float m2 = fmaxf(c6, c7);
          float best = fmaxf(fmaxf(m0, m1), m2);
          int a0 = (c0 == best) ? (c ^ 0) : 8;
          int a1i = (c1 == best) ? (c ^ 1) : 8;
          int a2i = (c2 == best) ? (c ^ 2) : 8;
          int a3i = (c3 == best) ? (c ^ 3) : 8;
          int a4i = (c4 == best) ? (c ^ 4) : 8;
          int a5i = (c5 == best) ? (c ^ 5) : 8;
          int a6i = (c6 == best) ? (c ^ 6) : 8;
          int a7i = (c7 == best) ? (c ^ 7) : 8;
          int arg = min(min(min(a0, a1i), min(a2i, a3i)),
                        min(min(a4i, a5i), min(a6i, a7i)));
          v = best + emv[j];
          int wd = arg << (3 * c);
          wd |= dppi<QP1>(wd); wd |= dppi<QP2>(wd); wd |= dppi<HM>(wd);
          if ((lane & 7) == 0) sBP[t] = wd;
        }
      }
    }
    __syncthreads();

    // phase 4a: per-chunk exit->entry maps (all 8 exit states in parallel)
    if (w < 4) {
      const int u = lane >> 3;
      const int i = w * 8 + u;
      const int t0 = i * 16;
      const int te = (t0 + 16 < 512) ? (t0 + 16) : 511;
      int tag = c;
#pragma unroll
      for (int j = 16; j >= 1; --j) {
        int t = t0 + j;
        if (t <= te) tag = (sBP[t] >> (3 * tag)) & 7;
      }
      sMap[i * 8 + c] = tag;
    }
    __syncthreads();
    // phase 4b: compose maps -> chunk entry states
    if (tid == 0) {
      int cur = sTerm;
#pragma unroll 1
      for (int i = 31; i >= 0; --i) { cur = sMap[i * 8 + cur]; sEnt[i] = cur; }
    }
    __syncthreads();
    // phase 4c: emit tags per chunk (32 parallel lanes)
    if (w == 0 && lane < 32) {
      const int i = lane;
      const int t0 = i * 16;
      const int te = (t0 + 16 < 512) ? (t0 + 16) : 511;
      int tag = (i == 31) ? sTerm : sEnt[i + 1];
      if (i == 31) sTags[511] = (unsigned char)tag;
#pragma unroll
      for (int j = 16; j >= 1; --j) {
        int t = t0 + j;
        if (t <= te) { tag = (sBP[t] >> (3 * tag)) & 7; sTags[t - 1] = (unsigned char)tag; }
      }
    }
    __syncthreads();
    // phase 5: coalesced pred store
    float* outp = d_out + 1 + LOGITS_N + (size_t)seq * 512;
    outp[tid] = (float)sTags[tid];
  }
}

extern "C" void kernel_launch(void* const* d_in, const int* in_sizes, int n_in,
                              void* d_out, int out_size, void* d_ws, size_t ws_size,
                              hipStream_t stream) {
  const float* enc    = (const float*)d_in[0];
  const int*   labels = (const int*)  d_in[1];
  const float* W      = (const float*)d_in[2];
  const float* bias   = (const float*)d_in[3];
  const float* startT = (const float*)d_in[4];
  const float* endT   = (const float*)d_in[5];
  const float* trans  = (const float*)d_in[6];
  float* out = (float*)d_out;
  ushort* WB = (ushort*)d_ws;   // 3 x 64 KB frag-ready split weights

  init_kernel<<<dim3(128), dim3(256), 0, stream>>>(W, WB, out);
  proj_kernel<<<dim3(256), dim3(512), 0, stream>>>(enc, WB, bias, out);
  crf_kernel<<<dim3(384), dim3(512), 0, stream>>>(labels, startT, endT, trans, out);
}

// Round 6
// 227.296 us; speedup vs baseline: 1.2002x; 1.0505x over previous
//
#include <hip/hip_runtime.h>

#define NB 64
#define NT 512
#define NH 1024
#define NC 8
#define NK 3
#define BT (NB*NT)             // 32768
#define LOGITS_N (NK*BT*NC)    // 786432

typedef unsigned short ushort;
typedef unsigned int uint;
typedef __attribute__((ext_vector_type(8))) short short8v;
typedef __attribute__((ext_vector_type(4))) float float4v;
union S8 { short8v v; ushort u[8]; };

// DPP controls
#define QP1  0xB1   // quad_perm [1,0,3,2] -> lane^1
#define QP2  0x4E   // quad_perm [2,3,0,1] -> lane^2
#define ROR4 0x124  // row_ror:4  -> lane^4 (value must be 8-group replicated)
#define ROR8 0x128  // row_ror:8  -> exact lane^8 within 16-row
#define HM   0x141  // row_half_mirror -> exact lane^7 within 8

template<int CTRL>
__device__ __forceinline__ float dppf(float x) {
  return __int_as_float(__builtin_amdgcn_update_dpp(0, __float_as_int(x), CTRL, 0xF, 0xF, true));
}
template<int CTRL>
__device__ __forceinline__ int dppi(int x) {
  return __builtin_amdgcn_update_dpp(0, x, CTRL, 0xF, 0xF, true);
}

__device__ __forceinline__ void gload_lds16(const void* g, void* l) {
  __builtin_amdgcn_global_load_lds(
      (const __attribute__((address_space(1))) void*)g,
      (__attribute__((address_space(3))) void*)l, 16, 0, 0);
}

// ---------- init: W -> frag-ready 3-way bf16 split WB[3][16ci][4q][64l][8] --
// Array a (a=0,1,2) holds the a-th truncation-split bf16 of W.
// Element (ci,q,l,i): kkb=q>>1, jt=q&1; k = ci*64 + kkb*32 + (l>>4)*8 + i;
// j = jt*16 + (l&15); value = (j<24) ? W[j>>3][j&7][k] : 0.
__global__ __launch_bounds__(256) void init_kernel(const float* __restrict__ W,
                                                   ushort* __restrict__ WB,
                                                   float* __restrict__ out) {
  const int i = blockIdx.x * 256 + threadIdx.x;   // 0..32767
  const int ci = i >> 11;
  const int rem = i & 2047;
  const int q = rem >> 9;
  const int l = (rem >> 3) & 63;
  const int e = i & 7;
  const int k = ci * 64 + (q >> 1) * 32 + ((l >> 4) << 3) + e;
  const int j = (q & 1) * 16 + (l & 15);
  float v = 0.0f;
  if (j < 24) v = W[(j >> 3) * (NC * NH) + (j & 7) * NH + k];
  const uint b = __float_as_uint(v);
  const ushort h1 = (ushort)(b >> 16);
  const float f1 = __uint_as_float(b & 0xFFFF0000u);
  const float r1 = v - f1;
  const uint b2 = __float_as_uint(r1);
  const ushort h2 = (ushort)(b2 >> 16);
  const float f2 = __uint_as_float(b2 & 0xFFFF0000u);
  const float r2 = r1 - f2;
  const ushort h3 = (ushort)(__float_as_uint(r2) >> 16);
  WB[i] = h1;
  WB[32768 + i] = h2;
  WB[65536 + i] = h3;
  if (i == 0) out[0] = 0.0f;
}

// ---------- proj v13: 16-phase chunk rotation + 2 blocks/CU -----------------
// 512 blocks x 256 thr (4 waves). Block = 64 rows x full K=1024; 16 chunks of
// K=64, visited in order t^ (blockIdx&15): all resident blocks cover all 16
// column phases simultaneously -> whole-chip address stream touches full 4KB
// rows (all HBM channels), instead of the lockstep 256B-per-4KB panel that
// capped v7-v12 at ~1.6 TB/s. LDS 56KB (sA 2x16KB fp32 + sB 2x12KB bf16) ->
// 2 independent blocks/CU: one block's compute covers the other's vmcnt drain.
// Wave w owns rows w*16..+15 x ALL 24 cols. MFMA 16x16x32 bf16, 3+3 Dekker
// split (6 terms) -> logits ~1e-7 of fp32. C/D: col=lane&15,
// row=(lane>>4)*4+reg (m89-verified). Accumulation order across chunks is
// rotation-permuted per block -> sum unchanged (fp32 rounding noise ~2^-24).
__global__ __launch_bounds__(256, 2) void proj_kernel(const float* __restrict__ enc,
                                                      const ushort* __restrict__ WB,
                                                      const float* __restrict__ bias,
                                                      float* __restrict__ out) {
  __shared__ float  sA[2][4096];    // 32 KB
  __shared__ ushort sB[2][6144];    // 24 KB
  const int tid = threadIdx.x;
  const int lane = tid & 63;
  const int w = tid >> 6;           // 0..3
  const int row0 = blockIdx.x * 64;
  const int chrot = blockIdx.x & 15;
  const float* eb = enc + (size_t)row0 * 1024;

  float4v acc0 = {0.0f, 0.0f, 0.0f, 0.0f};
  float4v acc1 = {0.0f, 0.0f, 0.0f, 0.0f};

  // stage A chunk cx: 4 instrs/wave, each 1KB = 4 rows x 256B; source slot
  // pre-swizzled ^(r&15) so the frag-load ds_read_b128 is bank-schedulable.
  auto stageA = [&](int cx, int buf) {
#pragma unroll
    for (int i = 0; i < 4; ++i) {
      const int rbase = w * 16 + i * 4;
      const int r = rbase + (lane >> 4);
      const int s = (lane & 15) ^ (r & 15);
      gload_lds16(eb + (size_t)r * 1024 + cx * 64 + s * 4, &sA[buf][rbase * 64]);
    }
  };
  // stage B chunk cx: 3 instrs/wave (splits 0..2, q=w), lane-linear frag-ready
  auto stageB = [&](int cx, int buf) {
#pragma unroll
    for (int i = 0; i < 3; ++i) {
      const int u = i * 4 + w;       // [split i][q=w]
      gload_lds16(WB + i * 32768 + cx * 2048 + w * 512 + lane * 8,
                  &sB[buf][u * 512]);
    }
  };

  auto compute = [&](int buf) {
    const float* ar = &sA[buf][(w * 16 + (lane & 15)) * 64];
    const ushort* sBf = &sB[buf][0];
    const int rx = lane & 15;
    const int g = lane >> 4;
#pragma unroll
    for (int kkb = 0; kkb < 2; ++kkb) {
      const int s0 = kkb * 8 + g * 2;
      const float4 e0 = *(const float4*)&ar[(s0 ^ rx) * 4];
      const float4 e1 = *(const float4*)&ar[((s0 + 1) ^ rx) * 4];
      S8 a1, a2, a3;
      const float vals[8] = {e0.x, e0.y, e0.z, e0.w, e1.x, e1.y, e1.z, e1.w};
#pragma unroll
      for (int t = 0; t < 8; ++t) {
        const float v = vals[t];
        const uint b = __float_as_uint(v);
        a1.u[t] = (ushort)(b >> 16);
        const float f1 = __uint_as_float(b & 0xFFFF0000u);
        const float r1 = v - f1;
        const uint b2 = __float_as_uint(r1);
        a2.u[t] = (ushort)(b2 >> 16);
        const float f2 = __uint_as_float(b2 & 0xFFFF0000u);
        const float r2 = r1 - f2;
        a3.u[t] = (ushort)(__float_as_uint(r2) >> 16);
      }
#pragma unroll
      for (int jt = 0; jt < 2; ++jt) {
        const int q = kkb * 2 + jt;
        const short8v w1 = *(const short8v*)&sBf[0 * 2048 + q * 512 + lane * 8];
        const short8v w2 = *(const short8v*)&sBf[1 * 2048 + q * 512 + lane * 8];
        const short8v w3 = *(const short8v*)&sBf[2 * 2048 + q * 512 + lane * 8];
        float4v acc = jt ? acc1 : acc0;
        acc = __builtin_amdgcn_mfma_f32_16x16x32_bf16(a1.v, w1, acc, 0, 0, 0);
        acc = __builtin_amdgcn_mfma_f32_16x16x32_bf16(a2.v, w1, acc, 0, 0, 0);
        acc = __builtin_amdgcn_mfma_f32_16x16x32_bf16(a1.v, w2, acc, 0, 0, 0);
        acc = __builtin_amdgcn_mfma_f32_16x16x32_bf16(a2.v, w2, acc, 0, 0, 0);
        acc = __builtin_amdgcn_mfma_f32_16x16x32_bf16(a3.v, w1, acc, 0, 0, 0);
        acc = __builtin_amdgcn_mfma_f32_16x16x32_bf16(a1.v, w3, acc, 0, 0, 0);
        if (jt) acc1 = acc; else acc0 = acc;
      }
    }
  };

  stageA(chrot, 0);                 // t=0 -> cx = 0 ^ chrot
  stageB(chrot, 0);
  __syncthreads();                  // chunk 0 resident

#pragma unroll 1
  for (int t = 0; t < 16; ++t) {
    const int buf = t & 1;
    if (t < 15) {
      const int cx = (t + 1) ^ chrot;
      stageA(cx, buf ^ 1);
      stageB(cx, buf ^ 1);
    }
    compute(buf);
    __syncthreads();                // drains prefetch; buf free next iter
  }

  // epilogue: direct stores from MFMA C/D layout (+bias); no LDS reduce.
  const int g = lane >> 4, cx2 = lane & 15;
#pragma unroll
  for (int jt = 0; jt < 2; ++jt) {
    const int j = jt * 16 + cx2;
    if (j < 24) {
      const float bj = bias[j];
      const float4v acc = jt ? acc1 : acc0;
      float* ob = out + 1 + (size_t)(j >> 3) * (BT * 8) + (j & 7);
#pragma unroll
      for (int qq = 0; qq < 4; ++qq) {
        const int grow = row0 + w * 16 + g * 4 + qq;
        ob[(size_t)grow * 8] = acc[qq] + bj;
      }
    }
  }
}

// ---------- CRF v6: chunk-parallel scan (unchanged) --------------------------
__global__ __launch_bounds__(512) void crf_kernel(const int* __restrict__ labels,
                                                  const float* __restrict__ startT,
                                                  const float* __restrict__ endT,
                                                  const float* __restrict__ trans,
                                                  float* __restrict__ d_out) {
  __shared__ float sA[32 * 64];          // chunk matrices [i][p][c]
  __shared__ float sVB[32 * 8];          // vit boundary vectors
  __shared__ int   sBP[512];             // vit packed bp words
  __shared__ int   sMap[32 * 8];         // vit exit->entry maps
  __shared__ int   sEnt[32];             // vit chunk entry states
  __shared__ float sRed[32];             // fwd numerator partials
  __shared__ unsigned char sTags[512];
  __shared__ int sTerm;

  const int tid = threadIdx.x;
  const int lane = tid & 63;
  const int w = tid >> 6;
  const int c = lane & 7;
  const int p = (lane >> 3) & 7;
  const int role = (blockIdx.x >= 192);
  const int seq = role ? blockIdx.x - 192 : blockIdx.x;
  const int k = seq >> 6, b = seq & 63;
  const float* em = d_out + 1 + ((size_t)k * BT + (size_t)b * 512) * 8;
  const float* trk = trans + k * 64;
  const int* lab = labels + b * (NK * NT) + k * NT;

  float Txc[8];
#pragma unroll
  for (int kk = 0; kk < 8; ++kk) Txc[kk] = trk[(c ^ kk) * 8 + c];
  const float Tpc = trk[p * 8 + c];
  const float startc = startT[k * 8 + c];
  const float endc = endT[k * 8 + c];

  if (!role) {
    // ========================= FORWARD (logZ + loss) ========================
    float Mxc[8];
#pragma unroll
    for (int kk = 0; kk < 8; ++kk) Mxc[kk] = __expf(Txc[kk]);

    // phase 1: linear-domain chunk matrices, constant 2^-32 renorm at step 8
#pragma unroll 1
    for (int it = 0; it < 4; ++it) {
      const int i = w * 4 + it;
      const int t0 = i * 16;
      const int te = (t0 + 16 < 512) ? (t0 + 16) : 511;
      float EX[16];
      EX[0] = em[(t0 + 1) * 8 + c];             // raw em for init
#pragma unroll
      for (int j = 1; j < 16; ++j) {
        int t = t0 + 1 + j;
        EX[j] = (t <= te) ? __expf(em[t * 8 + c]) : 1.0f;
      }
      float V = __expf(Tpc + EX[0]);
#pragma unroll
      for (int j = 1; j < 16; ++j) {
        int t = t0 + 1 + j;
        if (t <= te) {
          float x1 = dppf<QP1>(V), x2 = dppf<QP2>(V), x3 = dppf<QP2>(x1);
          float x7 = dppf<HM>(V), x6 = dppf<QP1>(x7), x5 = dppf<QP2>(x7), x4 = dppf<QP2>(x6);
          float s01 = fmaf(x1, Mxc[1], V * Mxc[0]);
          float s23 = fmaf(x3, Mxc[3], x2 * Mxc[2]);
          float s45 = fmaf(x5, Mxc[5], x4 * Mxc[4]);
          float s67 = fmaf(x7, Mxc[7], x6 * Mxc[6]);
          V = ((s01 + s23) + (s45 + s67)) * EX[j];
        }
        if (j == 8) V *= 0x1p-32f;              // exact pow2 renorm (uniform)
      }
      sA[i * 64 + lane] = V;
    }
    __syncthreads();

    float logZ = 0.0f;
    if (w == 0) {
      // phase 2: 32-step alpha scan
      float al = __expf(startc + em[c]);
      float lz = 0.0f;
#pragma unroll 1
      for (int i = 0; i < 32; ++i) {
        const float* Ai = &sA[i * 64];
        float A0 = Ai[(c ^ 0) * 8 + c], A1 = Ai[(c ^ 1) * 8 + c];
        float A2 = Ai[(c ^ 2) * 8 + c], A3 = Ai[(c ^ 3) * 8 + c];
        float A4 = Ai[(c ^ 4) * 8 + c], A5 = Ai[(c ^ 5) * 8 + c];
        float A6 = Ai[(c ^ 6) * 8 + c], A7 = Ai[(c ^ 7) * 8 + c];
        float a1 = dppf<QP1>(al), a2 = dppf<QP2>(al), a3 = dppf<QP2>(a1);
        float a4 = dppf<ROR4>(al), a5 = dppf<ROR4>(a1), a6 = dppf<ROR4>(a2), a7 = dppf<ROR4>(a3);
        float s01 = fmaf(a1, A1, al * A0);
        float s23 = fmaf(a3, A3, a2 * A2);
        float s45 = fmaf(a5, A5, a4 * A4);
        float s67 = fmaf(a7, A7, a6 * A6);
        float s = (s01 + s23) + (s45 + s67);
        float ss = s;
        ss += dppf<QP1>(ss); ss += dppf<QP2>(ss); ss += dppf<ROR4>(ss);
        lz += __logf(ss);
        al = s * (1.0f / ss);
      }
      float se = al * __expf(endc);
      se += dppf<QP1>(se); se += dppf<QP2>(se); se += dppf<ROR4>(se);
      logZ = lz + __logf(se) + 1024.0f * 0.69314718055994531f;  // 32 chunks x 32 ln2
    } else {
      // phase 2 (waves 1-7): gold-path numerator
      int idx = (w - 1) * 64 + lane;            // 0..447
      float ns = 0.0f;
      {
        int tg = lab[idx];
        ns += em[(size_t)idx * 8 + tg] + trk[tg * 8 + lab[idx + 1]];
      }
      if (idx < 64) {
        int t = idx + 448;
        int tg = lab[t];
        ns += em[(size_t)t * 8 + tg];
        if (t < 511) ns += trk[tg * 8 + lab[t + 1]];
      }
      ns += dppf<QP1>(ns); ns += dppf<QP2>(ns); ns += dppf<HM>(ns); ns += dppf<ROR8>(ns);
      if ((lane & 15) == 0) sRed[(w - 1) * 4 + (lane >> 4)] = ns;
    }
    __syncthreads();
    if (tid == 0) {
      float num = startT[k * 8 + lab[0]] + endT[k * 8 + lab[511]];
#pragma unroll
      for (int u = 0; u < 28; ++u) num += sRed[u];
      atomicAdd(d_out, logZ - num);
    }
  } else {
    // ========================= VITERBI (preds) ==============================
    // phase 1: max-plus chunk matrices
#pragma unroll 1
    for (int it = 0; it < 4; ++it) {
      const int i = w * 4 + it;
      const int t0 = i * 16;
      const int te = (t0 + 16 < 512) ? (t0 + 16) : 511;
      float emv[16];
#pragma unroll
      for (int j = 0; j < 16; ++j) {
        int t = t0 + 1 + j;
        emv[j] = (t <= te) ? em[t * 8 + c] : 0.0f;
      }
      float V = Tpc + emv[0];
#pragma unroll
      for (int j = 1; j < 16; ++j) {
        int t = t0 + 1 + j;
        if (t <= te) {
          float x1 = dppf<QP1>(V), x2 = dppf<QP2>(V), x3 = dppf<QP2>(x1);
          float x7 = dppf<HM>(V), x6 = dppf<QP1>(x7), x5 = dppf<QP2>(x7), x4 = dppf<QP2>(x6);
          float c0 = V + Txc[0], c1 = x1 + Txc[1], c2 = x2 + Txc[2], c3 = x3 + Txc[3];
          float c4 = x4 + Txc[4], c5 = x5 + Txc[5], c6 = x6 + Txc[6], c7 = x7 + Txc[7];
          float m0 = fmaxf(fmaxf(c0, c1), c2);
          float m1 = fmaxf(fmaxf(c3, c4), c5);
          float m2 = fmaxf(c6, c7);
          V = fmaxf(fmaxf(m0, m1), m2) + emv[j];
        }
      }
      sA[i * 64 + lane] = V;
    }
    __syncthreads();

    // phase 2: v scan (wave 0), store boundary vectors
    if (w == 0) {
      float v = startc + em[c];
#pragma unroll 1
      for (int i = 0; i < 32; ++i) {
        if (lane < 8) sVB[i * 8 + c] = v;
        const float* Ai = &sA[i * 64];
        float A0 = Ai[(c ^ 0) * 8 + c], A1 = Ai[(c ^ 1) * 8 + c];
        float A2 = Ai[(c ^ 2) * 8 + c], A3 = Ai[(c ^ 3) * 8 + c];
        float A4 = Ai[(c ^ 4) * 8 + c], A5 = Ai[(c ^ 5) * 8 + c];
        float A6 = Ai[(c ^ 6) * 8 + c], A7 = Ai[(c ^ 7) * 8 + c];
        float a1 = dppf<QP1>(v), a2 = dppf<QP2>(v), a3 = dppf<QP2>(a1);
        float a4 = dppf<ROR4>(v), a5 = dppf<ROR4>(a1), a6 = dppf<ROR4>(a2), a7 = dppf<ROR4>(a3);
        float c0 = v + A0, c1 = a1 + A1, c2 = a2 + A2, c3 = a3 + A3;
        float c4 = a4 + A4, c5 = a5 + A5, c6 = a6 + A6, c7 = a7 + A7;
        float m0 = fmaxf(fmaxf(c0, c1), c2);
        float m1 = fmaxf(fmaxf(c3, c4), c5);
        float m2 = fmaxf(c6, c7);
        v = fmaxf(fmaxf(m0, m1), m2);
      }
      float lv = v + endc;
      int li = c;
      {
        float ov; int oi; bool take;
        ov = dppf<QP1>(lv); oi = dppi<QP1>(li);
        take = (ov > lv) || (ov == lv && oi < li); lv = take ? ov : lv; li = take ? oi : li;
        ov = dppf<QP2>(lv); oi = dppi<QP2>(li);
        take = (ov > lv) || (ov == lv && oi < li); lv = take ? ov : lv; li = take ? oi : li;
        ov = dppf<ROR4>(lv); oi = dppi<ROR4>(li);
        take = (ov > lv) || (ov == lv && oi < li); lv = take ? ov : lv; li = take ? oi : li;
      }
      if (lane == 0) sTerm = li;
    }
    __syncthreads();

    // phase 3: exact bp recompute, 8 chunk-slots per wave (waves 0-3)
    if (w < 4) {
      const int u = lane >> 3;
      const int i = w * 8 + u;
      const int t0 = i * 16;
      const int te = (t0 + 16 < 512) ? (t0 + 16) : 511;
      float emv[16];
#pragma unroll
      for (int j = 0; j < 16; ++j) {
        int t = t0 + 1 + j;
        emv[j] = (t <= te) ? em[t * 8 + c] : 0.0f;
      }
      float v = sVB[i * 8 + c];
#pragma unroll
      for (int j = 0; j < 16; ++j) {
        int t = t0 + 1 + j;
        if (t <= te) {
          float x1 = dppf<QP1>(v), x2 = dppf<QP2>(v), x3 = dppf<QP2>(x1);
          float x7 = dppf<HM>(v), x6 = dppf<QP1>(x7), x5 = dppf<QP2>(x7), x4 = dppf<QP2>(x6);
          float c0 = v + Txc[0], c1 = x1 + Txc[1], c2 = x2 + Txc[2], c3 = x3 + Txc[3];
          float c4 = x4 + Txc[4], c5 = x5 + Txc[5], c6 = x6 + Txc[6], c7 = x7 + Txc[7];
          float m0 = fmaxf(fmaxf(c0, c1), c2);
          float m1 = fmaxf(fmaxf(c3, c4), c5);
          float m2 = fmaxf(c6, c7);
          float best = fmaxf(fmaxf(m0, m1), m2);
          int a0 = (c0 == best) ? (c ^ 0) : 8;
          int a1i = (c1 == best) ? (c ^ 1) : 8;
          int a2i = (c2 == best) ? (c ^ 2) : 8;
          int a3i = (c3 == best) ? (c ^ 3) : 8;
          int a4i = (c4 == best) ? (c ^ 4) : 8;
          int a5i = (c5 == best) ? (c ^ 5) : 8;
          int a6i = (c6 == best) ? (c ^ 6) : 8;
          int a7i = (c7 == best) ? (c ^ 7) : 8;
          int arg = min(min(min(a0, a1i), min(a2i, a3i)),
                        min(min(a4i, a5i), min(a6i, a7i)));
          v = best + emv[j];
          int wd = arg << (3 * c);
          wd |= dppi<QP1>(wd); wd |= dppi<QP2>(wd); wd |= dppi<HM>(wd);
          if ((lane & 7) == 0) sBP[t] = wd;
        }
      }
    }
    __syncthreads();

    // phase 4a: per-chunk exit->entry maps (all 8 exit states in parallel)
    if (w < 4) {
      const int u = lane >> 3;
      const int i = w * 8 + u;
      const int t0 = i * 16;
      const int te = (t0 + 16 < 512) ? (t0 + 16) : 511;
      int tag = c;
#pragma unroll
      for (int j = 16; j >= 1; --j) {
        int t = t0 + j;
        if (t <= te) tag = (sBP[t] >> (3 * tag)) & 7;
      }
      sMap[i * 8 + c] = tag;
    }
    __syncthreads();
    // phase 4b: compose maps -> chunk entry states
    if (tid == 0) {
      int cur = sTerm;
#pragma unroll 1
      for (int i = 31; i >= 0; --i) { cur = sMap[i * 8 + cur]; sEnt[i] = cur; }
    }
    __syncthreads();
    // phase 4c: emit tags per chunk (32 parallel lanes)
    if (w == 0 && lane < 32) {
      const int i = lane;
      const int t0 = i * 16;
      const int te = (t0 + 16 < 512) ? (t0 + 16) : 511;
      int tag = (i == 31) ? sTerm : sEnt[i + 1];
      if (i == 31) sTags[511] = (unsigned char)tag;
#pragma unroll
      for (int j = 16; j >= 1; --j) {
        int t = t0 + j;
        if (t <= te) { tag = (sBP[t] >> (3 * tag)) & 7; sTags[t - 1] = (unsigned char)tag; }
      }
    }
    __syncthreads();
    // phase 5: coalesced pred store
    float* outp = d_out + 1 + LOGITS_N + (size_t)seq * 512;
    outp[tid] = (float)sTags[tid];
  }
}

extern "C" void kernel_launch(void* const* d_in, const int* in_sizes, int n_in,
                              void* d_out, int out_size, void* d_ws, size_t ws_size,
                              hipStream_t stream) {
  const float* enc    = (const float*)d_in[0];
  const int*   labels = (const int*)  d_in[1];
  const float* W      = (const float*)d_in[2];
  const float* bias   = (const float*)d_in[3];
  const float* startT = (const float*)d_in[4];
  const float* endT   = (const float*)d_in[5];
  const float* trans  = (const float*)d_in[6];
  float* out = (float*)d_out;
  ushort* WB = (ushort*)d_ws;   // 3 x 64 KB frag-ready split weights

  init_kernel<<<dim3(128), dim3(256), 0, stream>>>(W, WB, out);
  proj_kernel<<<dim3(512), dim3(256), 0, stream>>>(enc, WB, bias, out);
  crf_kernel<<<dim3(384), dim3(512), 0, stream>>>(labels, startT, endT, trans, out);
}

// Round 7
// 226.176 us; speedup vs baseline: 1.2061x; 1.0050x over previous
//
#include <hip/hip_runtime.h>

#define NB 64
#define NT 512
#define NH 1024
#define NC 8
#define NK 3
#define BT (NB*NT)             // 32768
#define LOGITS_N (NK*BT*NC)    // 786432

typedef unsigned short ushort;
typedef unsigned int uint;
typedef __attribute__((ext_vector_type(8))) short short8v;
typedef __attribute__((ext_vector_type(4))) float float4v;
union S8 { short8v v; ushort u[8]; };

// DPP controls
#define QP1  0xB1   // quad_perm [1,0,3,2] -> lane^1
#define QP2  0x4E   // quad_perm [2,3,0,1] -> lane^2
#define ROR4 0x124  // row_ror:4  -> lane^4 (value must be 8-group replicated)
#define ROR8 0x128  // row_ror:8  -> exact lane^8 within 16-row
#define HM   0x141  // row_half_mirror -> exact lane^7 within 8

template<int CTRL>
__device__ __forceinline__ float dppf(float x) {
  return __int_as_float(__builtin_amdgcn_update_dpp(0, __float_as_int(x), CTRL, 0xF, 0xF, true));
}
template<int CTRL>
__device__ __forceinline__ int dppi(int x) {
  return __builtin_amdgcn_update_dpp(0, x, CTRL, 0xF, 0xF, true);
}

__device__ __forceinline__ void gload_lds16(const void* g, void* l) {
  __builtin_amdgcn_global_load_lds(
      (const __attribute__((address_space(1))) void*)g,
      (__attribute__((address_space(3))) void*)l, 16, 0, 0);
}

// ---------- init: W -> frag-ready 3-way bf16 split WB[3][16ci][4q][64l][8] --
__global__ __launch_bounds__(256) void init_kernel(const float* __restrict__ W,
                                                   ushort* __restrict__ WB,
                                                   float* __restrict__ out) {
  const int i = blockIdx.x * 256 + threadIdx.x;   // 0..32767
  const int ci = i >> 11;
  const int rem = i & 2047;
  const int q = rem >> 9;
  const int l = (rem >> 3) & 63;
  const int e = i & 7;
  const int k = ci * 64 + (q >> 1) * 32 + ((l >> 4) << 3) + e;
  const int j = (q & 1) * 16 + (l & 15);
  float v = 0.0f;
  if (j < 24) v = W[(j >> 3) * (NC * NH) + (j & 7) * NH + k];
  const uint b = __float_as_uint(v);
  const ushort h1 = (ushort)(b >> 16);
  const float f1 = __uint_as_float(b & 0xFFFF0000u);
  const float r1 = v - f1;
  const uint b2 = __float_as_uint(r1);
  const ushort h2 = (ushort)(b2 >> 16);
  const float f2 = __uint_as_float(b2 & 0xFFFF0000u);
  const float r2 = r1 - f2;
  const ushort h3 = (ushort)(__float_as_uint(r2) >> 16);
  WB[i] = h1;
  WB[32768 + i] = h2;
  WB[65536 + i] = h3;
  if (i == 0) out[0] = 0.0f;
}

// ---------- proj v14: depth-2 prefetch + counted vmcnt (T4) -----------------
// v13 + pipeline deepening. 512 blocks x 256 thr (4 waves), 64 rows x K=1024,
// 16 chunks of K=64 visited in order t^(blockIdx&15) (channel-phase spread).
// sA: 3 buffers (48KB) staged TWO chunks ahead — A is self-staged/self-read
// per wave (wave w rows w*16..+15), so no cross-wave hazard, no extra sync.
// sB: 2 buffers (24KB) staged one ahead; all-waves-read -> plain s_barrier
// after compute protects reuse. Per iter: issue B(t+1),A(t+2); then
// s_waitcnt vmcnt(11) — waits ONLY chunk-t's loads (11 = loads issued after
// B(t)); never drains to 0 mid-loop (T4). Tail: vmcnt(7)@14, vmcnt(0)@15.
// LDS 72KB -> 2 blocks/CU; in-flight/wave 7 -> 18.
__global__ __launch_bounds__(256, 2) void proj_kernel(const float* __restrict__ enc,
                                                      const ushort* __restrict__ WB,
                                                      const float* __restrict__ bias,
                                                      float* __restrict__ out) {
  __shared__ float  sA[3][4096];    // 48 KB triple buffer
  __shared__ ushort sB[2][6144];    // 24 KB double buffer
  const int tid = threadIdx.x;
  const int lane = tid & 63;
  const int w = tid >> 6;           // 0..3
  const int row0 = blockIdx.x * 64;
  const int chrot = blockIdx.x & 15;
  const float* eb = enc + (size_t)row0 * 1024;

  float4v acc0 = {0.0f, 0.0f, 0.0f, 0.0f};
  float4v acc1 = {0.0f, 0.0f, 0.0f, 0.0f};

  // stage A chunk for step t (cx = t^chrot) into sA[t%3].
  auto stageA = [&](int t) {
    const int cx = t ^ chrot;
    float* dst = &sA[t % 3][0];
#pragma unroll
    for (int i = 0; i < 4; ++i) {
      const int rbase = w * 16 + i * 4;
      const int r = rbase + (lane >> 4);
      const int s = (lane & 15) ^ (r & 15);
      gload_lds16(eb + (size_t)r * 1024 + cx * 64 + s * 4, &dst[rbase * 64]);
    }
  };
  // stage B chunk for step t into sB[t&1] (3 instrs/wave, lane-linear).
  auto stageB = [&](int t) {
    const int cx = t ^ chrot;
    ushort* dst = &sB[t & 1][0];
#pragma unroll
    for (int i = 0; i < 3; ++i) {
      const int u = i * 4 + w;       // [split i][q=w]
      gload_lds16(WB + i * 32768 + cx * 2048 + w * 512 + lane * 8,
                  &dst[u * 512]);
    }
  };

  auto compute = [&](int abuf, int bbuf) {
    const float* ar = &sA[abuf][(w * 16 + (lane & 15)) * 64];
    const ushort* sBf = &sB[bbuf][0];
    const int rx = lane & 15;
    const int g = lane >> 4;
#pragma unroll
    for (int kkb = 0; kkb < 2; ++kkb) {
      const int s0 = kkb * 8 + g * 2;
      const float4 e0 = *(const float4*)&ar[(s0 ^ rx) * 4];
      const float4 e1 = *(const float4*)&ar[((s0 + 1) ^ rx) * 4];
      S8 a1, a2, a3;
      const float vals[8] = {e0.x, e0.y, e0.z, e0.w, e1.x, e1.y, e1.z, e1.w};
#pragma unroll
      for (int t = 0; t < 8; ++t) {
        const float v = vals[t];
        const uint b = __float_as_uint(v);
        a1.u[t] = (ushort)(b >> 16);
        const float f1 = __uint_as_float(b & 0xFFFF0000u);
        const float r1 = v - f1;
        const uint b2 = __float_as_uint(r1);
        a2.u[t] = (ushort)(b2 >> 16);
        const float f2 = __uint_as_float(b2 & 0xFFFF0000u);
        const float r2 = r1 - f2;
        a3.u[t] = (ushort)(__float_as_uint(r2) >> 16);
      }
#pragma unroll
      for (int jt = 0; jt < 2; ++jt) {
        const int q = kkb * 2 + jt;
        const short8v w1 = *(const short8v*)&sBf[0 * 2048 + q * 512 + lane * 8];
        const short8v w2 = *(const short8v*)&sBf[1 * 2048 + q * 512 + lane * 8];
        const short8v w3 = *(const short8v*)&sBf[2 * 2048 + q * 512 + lane * 8];
        float4v acc = jt ? acc1 : acc0;
        acc = __builtin_amdgcn_mfma_f32_16x16x32_bf16(a1.v, w1, acc, 0, 0, 0);
        acc = __builtin_amdgcn_mfma_f32_16x16x32_bf16(a2.v, w1, acc, 0, 0, 0);
        acc = __builtin_amdgcn_mfma_f32_16x16x32_bf16(a1.v, w2, acc, 0, 0, 0);
        acc = __builtin_amdgcn_mfma_f32_16x16x32_bf16(a2.v, w2, acc, 0, 0, 0);
        acc = __builtin_amdgcn_mfma_f32_16x16x32_bf16(a3.v, w1, acc, 0, 0, 0);
        acc = __builtin_amdgcn_mfma_f32_16x16x32_bf16(a1.v, w3, acc, 0, 0, 0);
        if (jt) acc1 = acc; else acc0 = acc;
      }
    }
  };

  // prologue: A(0), B(0), A(1) in flight
  stageA(0);
  stageB(0);
  stageA(1);

#pragma unroll 1
  for (int t = 0; t < 16; ++t) {
    if (t + 1 < 16) stageB(t + 1);
    if (t + 2 < 16) stageA(t + 2);
    // wait chunk-t's loads only (counted, FIFO: after B(t) come A(t+1)4,B(t+1)3,A(t+2)4)
    if (t < 14)       asm volatile("s_waitcnt vmcnt(11)" ::: "memory");
    else if (t == 14) asm volatile("s_waitcnt vmcnt(7)" ::: "memory");
    else              asm volatile("s_waitcnt vmcnt(0)" ::: "memory");
    __builtin_amdgcn_s_barrier();            // all waves' chunk-t parts visible
    asm volatile("" ::: "memory");
    compute(t % 3, t & 1);
    asm volatile("" ::: "memory");
    __builtin_amdgcn_s_barrier();            // sB[t&1] free for stageB(t+2)
  }

  // epilogue: direct stores from MFMA C/D layout (+bias); no LDS reduce.
  const int g = lane >> 4, cx2 = lane & 15;
#pragma unroll
  for (int jt = 0; jt < 2; ++jt) {
    const int j = jt * 16 + cx2;
    if (j < 24) {
      const float bj = bias[j];
      const float4v acc = jt ? acc1 : acc0;
      float* ob = out + 1 + (size_t)(j >> 3) * (BT * 8) + (j & 7);
#pragma unroll
      for (int qq = 0; qq < 4; ++qq) {
        const int grow = row0 + w * 16 + g * 4 + qq;
        ob[(size_t)grow * 8] = acc[qq] + bj;
      }
    }
  }
}

// ---------- CRF v6: chunk-parallel scan (unchanged) --------------------------
__global__ __launch_bounds__(512) void crf_kernel(const int* __restrict__ labels,
                                                  const float* __restrict__ startT,
                                                  const float* __restrict__ endT,
                                                  const float* __restrict__ trans,
                                                  float* __restrict__ d_out) {
  __shared__ float sA[32 * 64];          // chunk matrices [i][p][c]
  __shared__ float sVB[32 * 8];          // vit boundary vectors
  __shared__ int   sBP[512];             // vit packed bp words
  __shared__ int   sMap[32 * 8];         // vit exit->entry maps
  __shared__ int   sEnt[32];             // vit chunk entry states
  __shared__ float sRed[32];             // fwd numerator partials
  __shared__ unsigned char sTags[512];
  __shared__ int sTerm;

  const int tid = threadIdx.x;
  const int lane = tid & 63;
  const int w = tid >> 6;
  const int c = lane & 7;
  const int p = (lane >> 3) & 7;
  const int role = (blockIdx.x >= 192);
  const int seq = role ? blockIdx.x - 192 : blockIdx.x;
  const int k = seq >> 6, b = seq & 63;
  const float* em = d_out + 1 + ((size_t)k * BT + (size_t)b * 512) * 8;
  const float* trk = trans + k * 64;
  const int* lab = labels + b * (NK * NT) + k * NT;

  float Txc[8];
#pragma unroll
  for (int kk = 0; kk < 8; ++kk) Txc[kk] = trk[(c ^ kk) * 8 + c];
  const float Tpc = trk[p * 8 + c];
  const float startc = startT[k * 8 + c];
  const float endc = endT[k * 8 + c];

  if (!role) {
    // ========================= FORWARD (logZ + loss) ========================
    float Mxc[8];
#pragma unroll
    for (int kk = 0; kk < 8; ++kk) Mxc[kk] = __expf(Txc[kk]);

    // phase 1: linear-domain chunk matrices, constant 2^-32 renorm at step 8
#pragma unroll 1
    for (int it = 0; it < 4; ++it) {
      const int i = w * 4 + it;
      const int t0 = i * 16;
      const int te = (t0 + 16 < 512) ? (t0 + 16) : 511;
      float EX[16];
      EX[0] = em[(t0 + 1) * 8 + c];             // raw em for init
#pragma unroll
      for (int j = 1; j < 16; ++j) {
        int t = t0 + 1 + j;
        EX[j] = (t <= te) ? __expf(em[t * 8 + c]) : 1.0f;
      }
      float V = __expf(Tpc + EX[0]);
#pragma unroll
      for (int j = 1; j < 16; ++j) {
        int t = t0 + 1 + j;
        if (t <= te) {
          float x1 = dppf<QP1>(V), x2 = dppf<QP2>(V), x3 = dppf<QP2>(x1);
          float x7 = dppf<HM>(V), x6 = dppf<QP1>(x7), x5 = dppf<QP2>(x7), x4 = dppf<QP2>(x6);
          float s01 = fmaf(x1, Mxc[1], V * Mxc[0]);
          float s23 = fmaf(x3, Mxc[3], x2 * Mxc[2]);
          float s45 = fmaf(x5, Mxc[5], x4 * Mxc[4]);
          float s67 = fmaf(x7, Mxc[7], x6 * Mxc[6]);
          V = ((s01 + s23) + (s45 + s67)) * EX[j];
        }
        if (j == 8) V *= 0x1p-32f;              // exact pow2 renorm (uniform)
      }
      sA[i * 64 + lane] = V;
    }
    __syncthreads();

    float logZ = 0.0f;
    if (w == 0) {
      // phase 2: 32-step alpha scan
      float al = __expf(startc + em[c]);
      float lz = 0.0f;
#pragma unroll 1
      for (int i = 0; i < 32; ++i) {
        const float* Ai = &sA[i * 64];
        float A0 = Ai[(c ^ 0) * 8 + c], A1 = Ai[(c ^ 1) * 8 + c];
        float A2 = Ai[(c ^ 2) * 8 + c], A3 = Ai[(c ^ 3) * 8 + c];
        float A4 = Ai[(c ^ 4) * 8 + c], A5 = Ai[(c ^ 5) * 8 + c];
        float A6 = Ai[(c ^ 6) * 8 + c], A7 = Ai[(c ^ 7) * 8 + c];
        float a1 = dppf<QP1>(al), a2 = dppf<QP2>(al), a3 = dppf<QP2>(a1);
        float a4 = dppf<ROR4>(al), a5 = dppf<ROR4>(a1), a6 = dppf<ROR4>(a2), a7 = dppf<ROR4>(a3);
        float s01 = fmaf(a1, A1, al * A0);
        float s23 = fmaf(a3, A3, a2 * A2);
        float s45 = fmaf(a5, A5, a4 * A4);
        float s67 = fmaf(a7, A7, a6 * A6);
        float s = (s01 + s23) + (s45 + s67);
        float ss = s;
        ss += dppf<QP1>(ss); ss += dppf<QP2>(ss); ss += dppf<ROR4>(ss);
        lz += __logf(ss);
        al = s * (1.0f / ss);
      }
      float se = al * __expf(endc);
      se += dppf<QP1>(se); se += dppf<QP2>(se); se += dppf<ROR4>(se);
      logZ = lz + __logf(se) + 1024.0f * 0.69314718055994531f;  // 32 chunks x 32 ln2
    } else {
      // phase 2 (waves 1-7): gold-path numerator
      int idx = (w - 1) * 64 + lane;            // 0..447
      float ns = 0.0f;
      {
        int tg = lab[idx];
        ns += em[(size_t)idx * 8 + tg] + trk[tg * 8 + lab[idx + 1]];
      }
      if (idx < 64) {
        int t = idx + 448;
        int tg = lab[t];
        ns += em[(size_t)t * 8 + tg];
        if (t < 511) ns += trk[tg * 8 + lab[t + 1]];
      }
      ns += dppf<QP1>(ns); ns += dppf<QP2>(ns); ns += dppf<HM>(ns); ns += dppf<ROR8>(ns);
      if ((lane & 15) == 0) sRed[(w - 1) * 4 + (lane >> 4)] = ns;
    }
    __syncthreads();
    if (tid == 0) {
      float num = startT[k * 8 + lab[0]] + endT[k * 8 + lab[511]];
#pragma unroll
      for (int u = 0; u < 28; ++u) num += sRed[u];
      atomicAdd(d_out, logZ - num);
    }
  } else {
    // ========================= VITERBI (preds) ==============================
    // phase 1: max-plus chunk matrices
#pragma unroll 1
    for (int it = 0; it < 4; ++it) {
      const int i = w * 4 + it;
      const int t0 = i * 16;
      const int te = (t0 + 16 < 512) ? (t0 + 16) : 511;
      float emv[16];
#pragma unroll
      for (int j = 0; j < 16; ++j) {
        int t = t0 + 1 + j;
        emv[j] = (t <= te) ? em[t * 8 + c] : 0.0f;
      }
      float V = Tpc + emv[0];
#pragma unroll
      for (int j = 1; j < 16; ++j) {
        int t = t0 + 1 + j;
        if (t <= te) {
          float x1 = dppf<QP1>(V), x2 = dppf<QP2>(V), x3 = dppf<QP2>(x1);
          float x7 = dppf<HM>(V), x6 = dppf<QP1>(x7), x5 = dppf<QP2>(x7), x4 = dppf<QP2>(x6);
          float c0 = V + Txc[0], c1 = x1 + Txc[1], c2 = x2 + Txc[2], c3 = x3 + Txc[3];
          float c4 = x4 + Txc[4], c5 = x5 + Txc[5], c6 = x6 + Txc[6], c7 = x7 + Txc[7];
          float m0 = fmaxf(fmaxf(c0, c1), c2);
          float m1 = fmaxf(fmaxf(c3, c4), c5);
          float m2 = fmaxf(c6, c7);
          V = fmaxf(fmaxf(m0, m1), m2) + emv[j];
        }
      }
      sA[i * 64 + lane] = V;
    }
    __syncthreads();

    // phase 2: v scan (wave 0), store boundary vectors
    if (w == 0) {
      float v = startc + em[c];
#pragma unroll 1
      for (int i = 0; i < 32; ++i) {
        if (lane < 8) sVB[i * 8 + c] = v;
        const float* Ai = &sA[i * 64];
        float A0 = Ai[(c ^ 0) * 8 + c], A1 = Ai[(c ^ 1) * 8 + c];
        float A2 = Ai[(c ^ 2) * 8 + c], A3 = Ai[(c ^ 3) * 8 + c];
        float A4 = Ai[(c ^ 4) * 8 + c], A5 = Ai[(c ^ 5) * 8 + c];
        float A6 = Ai[(c ^ 6) * 8 + c], A7 = Ai[(c ^ 7) * 8 + c];
        float a1 = dppf<QP1>(v), a2 = dppf<QP2>(v), a3 = dppf<QP2>(a1);
        float a4 = dppf<ROR4>(v), a5 = dppf<ROR4>(a1), a6 = dppf<ROR4>(a2), a7 = dppf<ROR4>(a3);
        float c0 = v + A0, c1 = a1 + A1, c2 = a2 + A2, c3 = a3 + A3;
        float c4 = a4 + A4, c5 = a5 + A5, c6 = a6 + A6, c7 = a7 + A7;
        float m0 = fmaxf(fmaxf(c0, c1), c2);
        float m1 = fmaxf(fmaxf(c3, c4), c5);
        float m2 = fmaxf(c6, c7);
        v = fmaxf(fmaxf(m0, m1), m2);
      }
      float lv = v + endc;
      int li = c;
      {
        float ov; int oi; bool take;
        ov = dppf<QP1>(lv); oi = dppi<QP1>(li);
        take = (ov > lv) || (ov == lv && oi < li); lv = take ? ov : lv; li = take ? oi : li;
        ov = dppf<QP2>(lv); oi = dppi<QP2>(li);
        take = (ov > lv) || (ov == lv && oi < li); lv = take ? ov : lv; li = take ? oi : li;
        ov = dppf<ROR4>(lv); oi = dppi<ROR4>(li);
        take = (ov > lv) || (ov == lv && oi < li); lv = take ? ov : lv; li = take ? oi : li;
      }
      if (lane == 0) sTerm = li;
    }
    __syncthreads();

    // phase 3: exact bp recompute, 8 chunk-slots per wave (waves 0-3)
    if (w < 4) {
      const int u = lane >> 3;
      const int i = w * 8 + u;
      const int t0 = i * 16;
      const int te = (t0 + 16 < 512) ? (t0 + 16) : 511;
      float emv[16];
#pragma unroll
      for (int j = 0; j < 16; ++j) {
        int t = t0 + 1 + j;
        emv[j] = (t <= te) ? em[t * 8 + c] : 0.0f;
      }
      float v = sVB[i * 8 + c];
#pragma unroll
      for (int j = 0; j < 16; ++j) {
        int t = t0 + 1 + j;
        if (t <= te) {
          float x1 = dppf<QP1>(v), x2 = dppf<QP2>(v), x3 = dppf<QP2>(x1);
          float x7 = dppf<HM>(v), x6 = dppf<QP1>(x7), x5 = dppf<QP2>(x7), x4 = dppf<QP2>(x6);
          float c0 = v + Txc[0], c1 = x1 + Txc[1], c2 = x2 + Txc[2], c3 = x3 + Txc[3];
          float c4 = x4 + Txc[4], c5 = x5 + Txc[5], c6 = x6 + Txc[6], c7 = x7 + Txc[7];
          float m0 = fmaxf(fmaxf(c0, c1), c2);
          float m1 = fmaxf(fmaxf(c3, c4), c5);
          float m2 = fmaxf(c6, c7);
          float best = fmaxf(fmaxf(m0, m1), m2);
          int a0 = (c0 == best) ? (c ^ 0) : 8;
          int a1i = (c1 == best) ? (c ^ 1) : 8;
          int a2i = (c2 == best) ? (c ^ 2) : 8;
          int a3i = (c3 == best) ? (c ^ 3) : 8;
          int a4i = (c4 == best) ? (c ^ 4) : 8;
          int a5i = (c5 == best) ? (c ^ 5) : 8;
          int a6i = (c6 == best) ? (c ^ 6) : 8;
          int a7i = (c7 == best) ? (c ^ 7) : 8;
          int arg = min(min(min(a0, a1i), min(a2i, a3i)),
                        min(min(a4i, a5i), min(a6i, a7i)));
          v = best + emv[j];
          int wd = arg << (3 * c);
          wd |= dppi<QP1>(wd); wd |= dppi<QP2>(wd); wd |= dppi<HM>(wd);
          if ((lane & 7) == 0) sBP[t] = wd;
        }
      }
    }
    __syncthreads();

    // phase 4a: per-chunk exit->entry maps (all 8 exit states in parallel)
    if (w < 4) {
      const int u = lane >> 3;
      const int i = w * 8 + u;
      const int t0 = i * 16;
      const int te = (t0 + 16 < 512) ? (t0 + 16) : 511;
      int tag = c;
#pragma unroll
      for (int j = 16; j >= 1; --j) {
        int t = t0 + j;
        if (t <= te) tag = (sBP[t] >> (3 * tag)) & 7;
      }
      sMap[i * 8 + c] = tag;
    }
    __syncthreads();
    // phase 4b: compose maps -> chunk entry states
    if (tid == 0) {
      int cur = sTerm;
#pragma unroll 1
      for (int i = 31; i >= 0; --i) { cur = sMap[i * 8 + cur]; sEnt[i] = cur; }
    }
    __syncthreads();
    // phase 4c: emit tags per chunk (32 parallel lanes)
    if (w == 0 && lane < 32) {
      const int i = lane;
      const int t0 = i * 16;
      const int te = (t0 + 16 < 512) ? (t0 + 16) : 511;
      int tag = (i == 31) ? sTerm : sEnt[i + 1];
      if (i == 31) sTags[511] = (unsigned char)tag;
#pragma unroll
      for (int j = 16; j >= 1; --j) {
        int t = t0 + j;
        if (t <= te) { tag = (sBP[t] >> (3 * tag)) & 7; sTags[t - 1] = (unsigned char)tag; }
      }
    }
    __syncthreads();
    // phase 5: coalesced pred store
    float* outp = d_out + 1 + LOGITS_N + (size_t)seq * 512;
    outp[tid] = (float)sTags[tid];
  }
}

extern "C" void kernel_launch(void* const* d_in, const int* in_sizes, int n_in,
                              void* d_out, int out_size, void* d_ws, size_t ws_size,
                              hipStream_t stream) {
  const float* enc    = (const float*)d_in[0];
  const int*   labels = (const int*)  d_in[1];
  const float* W      = (const float*)d_in[2];
  const float* bias   = (const float*)d_in[3];
  const float* startT = (const float*)d_in[4];
  const float* endT   = (const float*)d_in[5];
  const float* trans  = (const float*)d_in[6];
  float* out = (float*)d_out;
  ushort* WB = (ushort*)d_ws;   // 3 x 64 KB frag-ready split weights

  init_kernel<<<dim3(128), dim3(256), 0, stream>>>(W, WB, out);
  proj_kernel<<<dim3(512), dim3(256), 0, stream>>>(enc, WB, bias, out);
  crf_kernel<<<dim3(384), dim3(512), 0, stream>>>(labels, startT, endT, trans, out);
}